// Round 6
// baseline (357.600 us; speedup 1.0000x reference)
//
#include <hip/hip_runtime.h>
#include <math.h>

#define Hh 80
#define Ww 80
#define HW 6400
#define PS 6724      // 82*82 padded spatial
#define NB 4

typedef _Float16 half8 __attribute__((ext_vector_type(8)));
typedef _Float16 half4v __attribute__((ext_vector_type(4)));
typedef float f32x16 __attribute__((ext_vector_type(16)));

// ---------------------------------------------------------------------------
// Fused prep: 4 MFMA A-blobs (fp16) + 2 1x1 transposes + pad-zeroing of the
// 82x82 padded activation buffers (324 border sites per image).
// wblob: flat = ((((CT*NC + c)*9 + tap)*2 + h)*64 + lane)*8 + j
//   co = CT*32 + (lane&31);  ci = c*32 + h*16 + (lane>>5)*8 + j
// ---------------------------------------------------------------------------
__device__ inline void wblob_one(const float* src, _Float16* dst, int CI, int d) {
    int NC = CI / 32;
    int j = d & 7;
    int l = (d >> 3) & 63;
    int h = (d >> 9) & 1;
    int rest = d >> 10;
    int tap = rest % 9;
    rest /= 9;
    int c = rest % NC;
    int CT = rest / NC;
    int co = CT * 32 + (l & 31);
    int ci = c * 32 + h * 16 + (l >> 5) * 8 + j;
    dst[d] = (_Float16)src[((size_t)co * CI + ci) * 9 + tap];
}

__device__ inline int padsite(int p) {
    if (p < 82) return p;                       // row 0
    if (p < 164) return 81 * 82 + (p - 82);     // row 81
    if (p < 244) return (p - 163) * 82;         // col 0, rows 1..80
    return (p - 243) * 82 + 81;                 // col 81, rows 1..80
}

__global__ void prep_kernel(const float* __restrict__ w1, const float* __restrict__ w2,
                            const float* __restrict__ w3, const float* __restrict__ w4,
                            const float* __restrict__ vw, const float* __restrict__ ow,
                            _Float16* __restrict__ b1, _Float16* __restrict__ b2,
                            _Float16* __restrict__ b3, _Float16* __restrict__ b4,
                            float* __restrict__ tv, float* __restrict__ to,
                            int* __restrict__ qh_i, int* __restrict__ hA_i,
                            int* __restrict__ hB_i) {
    int idx = blockIdx.x * 256 + threadIdx.x;
    if (idx < 294912) { wblob_one(w1, b1, 256, idx); return; }
    idx -= 294912;
    if (idx < 147456) { wblob_one(w2, b2, 128, idx); return; }
    idx -= 147456;
    if (idx < 147456) { wblob_one(w3, b3, 128, idx); return; }
    idx -= 147456;
    if (idx < 147456) { wblob_one(w4, b4, 128, idx); return; }
    idx -= 147456;
    if (idx < 16384) { int co = idx & 127, ci = idx >> 7; tv[idx] = vw[co * 128 + ci]; return; }
    idx -= 16384;
    if (idx < 16384) { int co = idx & 127, ci = idx >> 7; to[idx] = ow[co * 128 + ci]; return; }
    idx -= 16384;
    if (idx < 165888) {  // q_h pads: 4n x 324 sites x 128 ints (256 halfs)
        int n = idx / 41472, rr = idx % 41472;
        int p = rr >> 7, k = rr & 127;
        qh_i[((size_t)n * PS + padsite(p)) * 128 + k] = 0;
        return;
    }
    idx -= 165888;
    if (idx < 82944) {   // hA pads: 4n x 324 x 64 ints (128 halfs)
        int n = idx / 20736, rr = idx % 20736;
        int p = rr >> 6, k = rr & 63;
        hA_i[((size_t)n * PS + padsite(p)) * 64 + k] = 0;
        return;
    }
    idx -= 82944;
    if (idx < 82944) {
        int n = idx / 20736, rr = idx % 20736;
        int p = rr >> 6, k = rr & 63;
        hB_i[((size_t)n * PS + padsite(p)) * 64 + k] = 0;
    }
}

// ---------------------------------------------------------------------------
// fp32 NCHW -> fp16 padded NHWC (82x82). grid (100, N), block 256.
// ---------------------------------------------------------------------------
template <int CI>
__global__ __launch_bounds__(256) void nchw_to_nhwc_h(
    const float* __restrict__ in, _Float16* __restrict__ out) {
    const int n = blockIdx.y, s0 = blockIdx.x * 64;
    const int t = threadIdx.x;
    constexpr int ST = CI + 8;
    __shared__ _Float16 T[64 * ST];
    for (int idx = t; idx < 64 * CI; idx += 256) {
        int ci = idx >> 6, sl = idx & 63;
        T[sl * ST + ci] = (_Float16)in[((size_t)n * CI + ci) * HW + s0 + sl];
    }
    __syncthreads();
    constexpr int NQ = CI / 8;
    for (int idx = t; idx < 64 * NQ; idx += 256) {
        int q = idx % NQ, sl = idx / NQ;
        int s = s0 + sl, yy = s / 80, xx = s % 80;
        *(int4*)(out + ((size_t)n * PS + (yy + 1) * 82 + (xx + 1)) * CI + q * 8) =
            *(const int4*)(&T[sl * ST + q * 8]);
    }
}

// ---------------------------------------------------------------------------
// MFMA implicit-GEMM 3x3 conv, pad=1, fp16 padded-NHWC in (82x82 rows).
// Barrier-free, no LDS. Wave tile = 64co (2 co-tiles) x 64sp (8x8 region,
// 2 site-halves). Depth-6 rotating register pipeline over the flattened
// (ci-chunk, tap, h) K-stream: 24 loads always in flight.
// grid: (100 regions, 2 co-halves, N), block 64.
// ACT 1: leaky -> fp16 padded NHWC. ACT 2: 10*tanh -> fp32 unpadded NHWC.
// ---------------------------------------------------------------------------
template <int CI, int ACT>
__global__ __launch_bounds__(64) void conv3x3_mfma(
    const _Float16* __restrict__ in, const _Float16* __restrict__ wblob,
    const float* __restrict__ bias, void* __restrict__ outp) {
    const int bx = blockIdx.x, ch = blockIdx.y, n = blockIdx.z;
    const int x0 = (bx % 10) * 8, y0 = (bx / 10) * 8;
    const int l = threadIdx.x;
    const int lane31 = l & 31, lhalf = l >> 5;
    const int lx = lane31 & 7, ly = lane31 >> 3;
    constexpr int NC = CI / 32;

    // site pointers (include +1,+1 pad shift and lhalf k-offset)
    const _Float16* p0 = in + ((size_t)n * PS + (y0 + ly + 1) * 82 + (x0 + lx + 1)) * CI + lhalf * 8;
    const _Float16* p1 = p0 + (size_t)4 * 82 * CI;
    const _Float16* wA0 = wblob + ((size_t)(ch * 2) * NC * 18) * 512 + l * 8;
    const _Float16* wA1 = wA0 + (size_t)NC * 18 * 512;

    f32x16 acc00 = {}, acc01 = {}, acc10 = {}, acc11 = {};
    half8 bB0[6], bB1[6], bA0[6], bA1[6];

    auto boffc = [](int t2) {
        int tap = t2 >> 1, h = t2 & 1;
        int dy = tap / 3, dx = tap % 3;
        return ((dy - 1) * 82 + (dx - 1)) * CI + h * 16;
    };

#pragma unroll
    for (int j = 0; j < 6; ++j) {
        const int off = boffc(j);
        bB0[j] = *(const half8*)(p0 + off);
        bB1[j] = *(const half8*)(p1 + off);
        bA0[j] = *(const half8*)(wA0 + j * 512);
        bA1[j] = *(const half8*)(wA1 + j * 512);
    }

    for (int c = 0; c < NC; ++c) {
        const int cOff = c * 32;
        const int cn = (c + 1 < NC) ? c + 1 : c;
        const int cnOff = cn * 32;
        const size_t aBase = (size_t)c * 18 * 512;
        const size_t aBaseN = (size_t)cn * 18 * 512;
#pragma unroll
        for (int g = 0; g < 3; ++g) {
#pragma unroll
            for (int j = 0; j < 6; ++j) {
                acc00 = __builtin_amdgcn_mfma_f32_32x32x16_f16(bA0[j], bB0[j], acc00, 0, 0, 0);
                acc01 = __builtin_amdgcn_mfma_f32_32x32x16_f16(bA0[j], bB1[j], acc01, 0, 0, 0);
                acc10 = __builtin_amdgcn_mfma_f32_32x32x16_f16(bA1[j], bB0[j], acc10, 0, 0, 0);
                acc11 = __builtin_amdgcn_mfma_f32_32x32x16_f16(bA1[j], bB1[j], acc11, 0, 0, 0);
                if (g < 2) {
                    const int t2L = (g + 1) * 6 + j;
                    const int off = boffc(t2L) + cOff;
                    bB0[j] = *(const half8*)(p0 + off);
                    bB1[j] = *(const half8*)(p1 + off);
                    bA0[j] = *(const half8*)(wA0 + aBase + t2L * 512);
                    bA1[j] = *(const half8*)(wA1 + aBase + t2L * 512);
                } else {
                    const int off = boffc(j) + cnOff;
                    bB0[j] = *(const half8*)(p0 + off);
                    bB1[j] = *(const half8*)(p1 + off);
                    bA0[j] = *(const half8*)(wA0 + aBaseN + j * 512);
                    bA1[j] = *(const half8*)(wA1 + aBaseN + j * 512);
                }
            }
        }
    }

    // epilogue: D col(site)=lane&31, row(co)=(reg&3)+8*(reg>>2)+4*(lane>>5)
#pragma unroll
    for (int ct = 0; ct < 2; ++ct) {
#pragma unroll
        for (int st = 0; st < 2; ++st) {
            const f32x16& acc = ct ? (st ? acc11 : acc10) : (st ? acc01 : acc00);
            const int y = y0 + st * 4 + ly, x = x0 + lx;
            const size_t rowbase = (ACT == 1)
                ? ((size_t)n * PS + (y + 1) * 82 + (x + 1)) * 128
                : ((size_t)n * HW + y * 80 + x) * 128;
#pragma unroll
            for (int q = 0; q < 4; ++q) {
                const int co0 = ch * 64 + ct * 32 + 8 * q + 4 * lhalf;
                float v[4];
#pragma unroll
                for (int i = 0; i < 4; ++i) {
                    float vv = acc[q * 4 + i] + bias[co0 + i];
                    if (ACT == 1) vv = (vv >= 0.f) ? vv : 0.1f * vv;
                    else vv = 10.f * tanhf(vv);
                    v[i] = vv;
                }
                if (ACT == 1) {
                    half4v hv = {(_Float16)v[0], (_Float16)v[1], (_Float16)v[2], (_Float16)v[3]};
                    *(half4v*)((_Float16*)outp + rowbase + co0) = hv;
                } else {
                    float4 fv = {v[0], v[1], v[2], v[3]};
                    *(float4*)((float*)outp + rowbase + co0) = fv;
                }
            }
        }
    }
}

// ---------------------------------------------------------------------------
// 1x1 conv (fp32 GEMM 128x128 over spatial). grid: (100, N), block 256.
// wt layout: [ci][128co].
// MODE 0: in fp32 NCHW  -> out v_s NHWC-16.
// MODE 1: in fp32 NHWC-16 ([n*8+hd][s][16]) -> out NCHW.
// ---------------------------------------------------------------------------
template <int MODE>
__global__ __launch_bounds__(256) void conv1x1_kernel(
    const float* __restrict__ in, const float* __restrict__ wt,
    const float* __restrict__ bias, float* __restrict__ out) {
    const int n = blockIdx.y;
    const int s0 = blockIdx.x * 64;
    const int t = threadIdx.x;
    const int sp_grp = t & 15;
    const int co_grp = t >> 4;

    __shared__ float Wl[16 * 128];
    __shared__ float Il[16 * 64];

    float acc[8][4];
#pragma unroll
    for (int i = 0; i < 8; ++i)
#pragma unroll
        for (int j = 0; j < 4; ++j) acc[i][j] = 0.f;

    for (int ch = 0; ch < 8; ++ch) {
        const int ci0 = ch * 16;
        __syncthreads();
        for (int i = t; i < 16 * 128; i += 256) Wl[i] = wt[ci0 * 128 + i];
        if (MODE == 0) {
            for (int i = t; i < 16 * 64; i += 256) {
                int ci = i >> 6, sp = i & 63;
                Il[i] = in[(size_t)(n * 128 + ci0 + ci) * HW + s0 + sp];
            }
        } else {
            int grp = t & 3, sp = t >> 2;
            const float4 v = *(const float4*)&in[(((size_t)(n * 8 + ch)) * HW + s0 + sp) * 16 + grp * 4];
            Il[(grp * 4 + 0) * 64 + sp] = v.x;
            Il[(grp * 4 + 1) * 64 + sp] = v.y;
            Il[(grp * 4 + 2) * 64 + sp] = v.z;
            Il[(grp * 4 + 3) * 64 + sp] = v.w;
        }
        __syncthreads();
#pragma unroll
        for (int ci = 0; ci < 16; ++ci) {
            float4 a0 = *(const float4*)&Wl[ci * 128 + co_grp * 8];
            float4 a1 = *(const float4*)&Wl[ci * 128 + co_grp * 8 + 4];
            float4 b  = *(const float4*)&Il[ci * 64 + sp_grp * 4];
            float av[8] = {a0.x, a0.y, a0.z, a0.w, a1.x, a1.y, a1.z, a1.w};
            float bv[4] = {b.x, b.y, b.z, b.w};
#pragma unroll
            for (int i = 0; i < 8; ++i)
#pragma unroll
                for (int j = 0; j < 4; ++j)
                    acc[i][j] = fmaf(av[i], bv[j], acc[i][j]);
        }
    }

#pragma unroll
    for (int i = 0; i < 8; ++i) {
        const int co = co_grp * 8 + i;
        const float bv = bias[co];
        if (MODE == 0) {
            const int hd = co >> 4, dd = co & 15;
#pragma unroll
            for (int j = 0; j < 4; ++j) {
                int s = s0 + sp_grp * 4 + j;
                out[((size_t)(n * 8 + hd) * HW + s) * 16 + dd] = acc[i][j] + bv;
            }
        } else {
#pragma unroll
            for (int j = 0; j < 4; ++j)
                out[(size_t)(n * 128 + co) * HW + s0 + sp_grp * 4 + j] = acc[i][j] + bv;
        }
    }
}

// ---------------------------------------------------------------------------
// Deformable attention, channel-vectorized + XCD-pinned slices.
// grid: (32 slices, 100 tiles), block 256 = 64 sites x 4 chgrp.
// v_s [nb][s][16] fp32; offs NHWC fp32; att NHWC-16 fp32.
// ---------------------------------------------------------------------------
__global__ __launch_bounds__(256) void deform_attn_kernel(
    const float* __restrict__ v_s, const float* __restrict__ offs,
    const float* __restrict__ ref, float* __restrict__ att) {
    const int slice = blockIdx.x;
    const int n = slice >> 3, hd = slice & 7;
    const int t = threadIdx.x;
    const int s = blockIdx.y * 64 + (t >> 2);
    const int d0 = (t & 3) * 4;
    const int nb = n * 8 + hd;

    const float4 cv = *(const float4*)&v_s[((size_t)nb * HW + s) * 16 + d0];
    const float rx = ref[(size_t)(n * HW + s) * 2 + 0] * 80.f - 0.5f;
    const float ry = ref[(size_t)(n * HW + s) * 2 + 1] * 80.f - 0.5f;

    const int e = (s >= 3200) ? 1 : 0;
    const float* ob0 = offs + ((size_t)n * HW + (2 * s - e * HW)) * 128 + hd * 16 + e;

    float4 sampled[8];
    float score[8];
#pragma unroll
    for (int p = 0; p < 8; ++p) {
        const float ox = ob0[2 * p];
        const float oy = ob0[128 + 2 * p];
        const float px = rx + ox;
        const float py = ry + oy;
        const float fx = floorf(px), fy = floorf(py);
        const int ix = (int)fx, iy = (int)fy;
        const float wx1 = px - fx, wy1 = py - fy;
        const float wx0 = 1.f - wx1, wy0 = 1.f - wy1;

        auto samp = [&](int xx, int yy) -> float4 {
            if (xx < 0 || xx >= Ww || yy < 0 || yy >= Hh) {
                float4 z = {0.f, 0.f, 0.f, 0.f};
                return z;
            }
            return *(const float4*)&v_s[((size_t)nb * HW + yy * Ww + xx) * 16 + d0];
        };
        const float4 v00 = samp(ix, iy);
        const float4 v01 = samp(ix + 1, iy);
        const float4 v10 = samp(ix, iy + 1);
        const float4 v11 = samp(ix + 1, iy + 1);
        const float w00 = wx0 * wy0, w01 = wx1 * wy0, w10 = wx0 * wy1, w11 = wx1 * wy1;
        float4 sv;
        sv.x = v00.x * w00 + v01.x * w01 + v10.x * w10 + v11.x * w11;
        sv.y = v00.y * w00 + v01.y * w01 + v10.y * w10 + v11.y * w11;
        sv.z = v00.z * w00 + v01.z * w01 + v10.z * w10 + v11.z * w11;
        sv.w = v00.w * w00 + v01.w * w01 + v10.w * w10 + v11.w * w11;
        sampled[p] = sv;
        float sc = sv.x * cv.x + sv.y * cv.y + sv.z * cv.z + sv.w * cv.w;
        sc += __shfl_xor(sc, 1);
        sc += __shfl_xor(sc, 2);
        score[p] = sc;
    }

    float m = score[0];
#pragma unroll
    for (int p = 1; p < 8; ++p) m = fmaxf(m, score[p]);
    float sum = 0.f, aw[8];
#pragma unroll
    for (int p = 0; p < 8; ++p) {
        aw[p] = __expf(score[p] - m);
        sum += aw[p];
    }
    const float inv = 1.f / sum;
    float4 o = {0.f, 0.f, 0.f, 0.f};
#pragma unroll
    for (int p = 0; p < 8; ++p) {
        o.x += aw[p] * sampled[p].x;
        o.y += aw[p] * sampled[p].y;
        o.z += aw[p] * sampled[p].z;
        o.w += aw[p] * sampled[p].w;
    }
    o.x *= inv; o.y *= inv; o.z *= inv; o.w *= inv;

    *(float4*)&att[((size_t)nb * HW + s) * 16 + d0] = o;
}

// ---------------------------------------------------------------------------
extern "C" void kernel_launch(void* const* d_in, const int* in_sizes, int n_in,
                              void* d_out, int out_size, void* d_ws, size_t ws_size,
                              hipStream_t stream) {
    const float* query = (const float*)d_in[0];
    const float* value = (const float*)d_in[1];
    const float* ref   = (const float*)d_in[2];
    const float* co_w1 = (const float*)d_in[3];
    const float* co_b1 = (const float*)d_in[4];
    const float* co_w2 = (const float*)d_in[5];
    const float* co_b2 = (const float*)d_in[6];
    const float* co_w3 = (const float*)d_in[7];
    const float* co_b3 = (const float*)d_in[8];
    const float* co_w4 = (const float*)d_in[9];
    const float* co_b4 = (const float*)d_in[10];
    const float* val_w = (const float*)d_in[11];
    const float* val_b = (const float*)d_in[12];
    const float* out_w = (const float*)d_in[13];
    const float* out_b = (const float*)d_in[14];

    char* ws = (char*)d_ws;
    size_t o = 0;
    auto alloc = [&](size_t bytes) { char* p = ws + o; o += (bytes + 255) & ~(size_t)255; return p; };

    _Float16* wb2 = (_Float16*)alloc(147456 * 2);
    _Float16* wb3 = (_Float16*)alloc(147456 * 2);
    _Float16* wb4 = (_Float16*)alloc(147456 * 2);
    float* wtv = (float*)alloc(16384 * 4);
    float* wto = (float*)alloc(16384 * 4);
    char* vsR = alloc(3276800 * 4);            // v_s fp32 [32][6400][16]
    float* v_s = (float*)vsR;
    _Float16* wb1 = (_Float16*)vsR;            // alias: wb1 dead before v_s written
    char* R1 = alloc((size_t)NB * PS * 256 * 2);  // 13.77 MB
    _Float16* q_h = (_Float16*)R1;             // fp16 padded NHWC [4][6724][256]
    float* o4 = (float*)R1;                    // fp32 NHWC [4][6400][128]; q_h dead
    char* R2 = alloc((size_t)NB * PS * 128 * 2 * 2);  // 13.78 MB
    _Float16* hA = (_Float16*)R2;              // fp16 padded NHWC [4][6724][128]
    _Float16* hB = (_Float16*)(R2 + (size_t)NB * PS * 128 * 2);
    float* att = (float*)R2;                   // NHWC-16 fp32; used after hA/hB dead

    // fused prep: wblobs + 1x1 transposes + pad zeroing (1101824 threads)
    prep_kernel<<<4304, 256, 0, stream>>>(co_w1, co_w2, co_w3, co_w4, val_w, out_w,
                                          wb1, wb2, wb3, wb4, wtv, wto,
                                          (int*)q_h, (int*)hA, (int*)hB);

    // transpose query to fp16 padded NHWC
    nchw_to_nhwc_h<256><<<dim3(100, NB), 256, 0, stream>>>(query, q_h);

    // conv1 (must precede val-conv: wb1 aliases v_s region)
    conv3x3_mfma<256, 1><<<dim3(100, 2, NB), 64, 0, stream>>>(q_h, wb1, co_b1, hA);

    // v = 1x1 conv(value) -> v_s (NHWC-16 fp32)
    conv1x1_kernel<0><<<dim3(100, NB), 256, 0, stream>>>(value, wtv, val_b, v_s);

    // rest of offset conv stack
    conv3x3_mfma<128, 1><<<dim3(100, 2, NB), 64, 0, stream>>>(hA, wb2, co_b2, hB);
    conv3x3_mfma<128, 1><<<dim3(100, 2, NB), 64, 0, stream>>>(hB, wb3, co_b3, hA);
    conv3x3_mfma<128, 2><<<dim3(100, 2, NB), 64, 0, stream>>>(hA, wb4, co_b4, o4);

    // deformable attention -> att (NHWC-16 fp32), XCD-pinned slices
    deform_attn_kernel<<<dim3(32, 100), 256, 0, stream>>>(v_s, o4, ref, att);

    // final 1x1 conv -> d_out (NCHW fp32)
    conv1x1_kernel<1><<<dim3(100, NB), 256, 0, stream>>>(att, wto, out_b, (float*)d_out);
}

// Round 7
// 337.162 us; speedup vs baseline: 1.0606x; 1.0606x over previous
//
#include <hip/hip_runtime.h>
#include <math.h>

#define Hh 80
#define Ww 80
#define HW 6400
#define PS 6724      // 82*82 padded spatial
#define NB 4

typedef _Float16 half8 __attribute__((ext_vector_type(8)));
typedef _Float16 half4v __attribute__((ext_vector_type(4)));
typedef float f32x16 __attribute__((ext_vector_type(16)));

// ---------------------------------------------------------------------------
// Fused prep: 4 MFMA A-blobs (fp16) + 2 1x1 transposes + pad-zeroing of the
// 82x82 padded activation buffers (324 border sites per image).
// wblob: flat = (CT*NC*18 + c*18 + tap*2 + h)*512 + lane*8 + j
//   co = CT*32 + (lane&31);  ci = c*32 + h*16 + (lane>>5)*8 + j
// ---------------------------------------------------------------------------
__device__ inline void wblob_one(const float* src, _Float16* dst, int CI, int d) {
    int NC = CI / 32;
    int j = d & 7;
    int l = (d >> 3) & 63;
    int h = (d >> 9) & 1;
    int rest = d >> 10;
    int tap = rest % 9;
    rest /= 9;
    int c = rest % NC;
    int CT = rest / NC;
    int co = CT * 32 + (l & 31);
    int ci = c * 32 + h * 16 + (l >> 5) * 8 + j;
    dst[d] = (_Float16)src[((size_t)co * CI + ci) * 9 + tap];
}

__device__ inline int padsite(int p) {
    if (p < 82) return p;                       // row 0
    if (p < 164) return 81 * 82 + (p - 82);     // row 81
    if (p < 244) return (p - 163) * 82;         // col 0, rows 1..80
    return (p - 243) * 82 + 81;                 // col 81, rows 1..80
}

__global__ void prep_kernel(const float* __restrict__ w1, const float* __restrict__ w2,
                            const float* __restrict__ w3, const float* __restrict__ w4,
                            const float* __restrict__ vw, const float* __restrict__ ow,
                            _Float16* __restrict__ b1, _Float16* __restrict__ b2,
                            _Float16* __restrict__ b3, _Float16* __restrict__ b4,
                            float* __restrict__ tv, float* __restrict__ to,
                            int* __restrict__ qh_i, int* __restrict__ hA_i,
                            int* __restrict__ hB_i) {
    int idx = blockIdx.x * 256 + threadIdx.x;
    if (idx < 294912) { wblob_one(w1, b1, 256, idx); return; }
    idx -= 294912;
    if (idx < 147456) { wblob_one(w2, b2, 128, idx); return; }
    idx -= 147456;
    if (idx < 147456) { wblob_one(w3, b3, 128, idx); return; }
    idx -= 147456;
    if (idx < 147456) { wblob_one(w4, b4, 128, idx); return; }
    idx -= 147456;
    if (idx < 16384) { int co = idx & 127, ci = idx >> 7; tv[idx] = vw[co * 128 + ci]; return; }
    idx -= 16384;
    if (idx < 16384) { int co = idx & 127, ci = idx >> 7; to[idx] = ow[co * 128 + ci]; return; }
    idx -= 16384;
    if (idx < 165888) {  // q_h pads: 4n x 324 sites x 128 ints (256 halfs)
        int n = idx / 41472, rr = idx % 41472;
        int p = rr >> 7, k = rr & 127;
        qh_i[((size_t)n * PS + padsite(p)) * 128 + k] = 0;
        return;
    }
    idx -= 165888;
    if (idx < 82944) {   // hA pads: 4n x 324 x 64 ints (128 halfs)
        int n = idx / 20736, rr = idx % 20736;
        int p = rr >> 6, k = rr & 63;
        hA_i[((size_t)n * PS + padsite(p)) * 64 + k] = 0;
        return;
    }
    idx -= 82944;
    if (idx < 82944) {
        int n = idx / 20736, rr = idx % 20736;
        int p = rr >> 6, k = rr & 63;
        hB_i[((size_t)n * PS + padsite(p)) * 64 + k] = 0;
    }
}

// ---------------------------------------------------------------------------
// query fp32 NCHW -> fp16 padded NHWC (82x82), XCD-pinned like the convs:
// grid (400), block 256: xcd = b&7 -> (n = xcd&3, half = xcd>>2).
// ---------------------------------------------------------------------------
__global__ __launch_bounds__(256) void q_transpose(
    const float* __restrict__ in, _Float16* __restrict__ out) {
    const int b = blockIdx.x;
    const int xcd = b & 7, n = xcd & 3, hi = xcd >> 2;
    const int s0 = hi * 3200 + (b >> 3) * 64;
    const int t = threadIdx.x;
    constexpr int CI = 256, ST = CI + 8;
    __shared__ _Float16 T[64 * ST];
    for (int idx = t; idx < 64 * CI; idx += 256) {
        int ci = idx >> 6, sl = idx & 63;
        T[sl * ST + ci] = (_Float16)in[((size_t)n * CI + ci) * HW + s0 + sl];
    }
    __syncthreads();
    constexpr int NQ = CI / 8;
    for (int idx = t; idx < 64 * NQ; idx += 256) {
        int q = idx % NQ, sl = idx / NQ;
        int s = s0 + sl, yy = s / 80, xx = s % 80;
        *(int4*)(out + ((size_t)n * PS + (yy + 1) * 82 + (xx + 1)) * CI + q * 8) =
            *(const int4*)(&T[sl * ST + q * 8]);
    }
}

// ---------------------------------------------------------------------------
// MFMA implicit-GEMM 3x3 conv, pad=1, fp16 padded-NHWC in (82x82 rows).
// Barrier-free, no LDS, XCD-pinned. Wave = 64co (2 co-tiles) x 32sp (8x4).
// Fully-unrolled K-stream (c asc, tap asc, h asc) with a depth-9 rotating
// register pipeline (27 loads in flight, all offsets compile-time).
// grid: flat (1600), block 64. b&7 -> XCD -> (n, image-half); b>>3 ->
// (co-half, region j in [0,100)) within that half-image.
// ACT 1: leaky -> fp16 padded NHWC. ACT 2: 10*tanh -> fp32 unpadded NHWC.
// ---------------------------------------------------------------------------
template <int CI, int ACT>
__global__ __launch_bounds__(64) void conv3x3_mfma(
    const _Float16* __restrict__ in, const _Float16* __restrict__ wblob,
    const float* __restrict__ bias, void* __restrict__ outp) {
    constexpr int NC = CI / 32;
    constexpr int NS = NC * 18;
    const int b = blockIdx.x;
    const int xcd = b & 7, n = xcd & 3, hi = xcd >> 2;
    const int r = b >> 3;
    const int ch = r & 1, j = r >> 1;              // j in [0,100)
    const int x0 = (j % 10) * 8, y0 = hi * 40 + (j / 10) * 4;
    const int l = threadIdx.x;
    const int lane31 = l & 31, lhalf = l >> 5;
    const int lx = lane31 & 7, ly = lane31 >> 3;

    const _Float16* p0 = in + ((size_t)n * PS + (y0 + ly + 1) * 82 + (x0 + lx + 1)) * CI + lhalf * 8;
    const _Float16* wA0 = wblob + ((size_t)(ch * 2) * NS) * 512 + l * 8;
    const _Float16* wA1 = wA0 + (size_t)NS * 512;

    f32x16 acc0 = {}, acc1 = {};
    half8 bB[9], bA0[9], bA1[9];

    // element offset of K-step t2 in the B (activation) stream
    auto boff = [](int t2) {
        int c = t2 / 18, u = t2 % 18;
        int tap = u >> 1, h = u & 1;
        int dy = tap / 3, dx = tap % 3;
        return ((dy - 1) * 82 + (dx - 1)) * CI + c * 32 + h * 16;
    };

#pragma unroll
    for (int t2 = 0; t2 < 9; ++t2) {
        bB[t2]  = *(const half8*)(p0 + boff(t2));
        bA0[t2] = *(const half8*)(wA0 + t2 * 512);
        bA1[t2] = *(const half8*)(wA1 + t2 * 512);
    }

#pragma unroll
    for (int t2 = 0; t2 < NS; ++t2) {
        const int slot = t2 % 9;
        acc0 = __builtin_amdgcn_mfma_f32_32x32x16_f16(bA0[slot], bB[slot], acc0, 0, 0, 0);
        acc1 = __builtin_amdgcn_mfma_f32_32x32x16_f16(bA1[slot], bB[slot], acc1, 0, 0, 0);
        if (t2 + 9 < NS) {
            const int t2p = t2 + 9;
            bB[slot]  = *(const half8*)(p0 + boff(t2p));
            bA0[slot] = *(const half8*)(wA0 + (size_t)t2p * 512);
            bA1[slot] = *(const half8*)(wA1 + (size_t)t2p * 512);
        }
    }

    // epilogue: D col(site)=lane&31, row(co)=(reg&3)+8*(reg>>2)+4*(lane>>5)
    const int y = y0 + ly, x = x0 + lx;
    const size_t rowbase = (ACT == 1)
        ? ((size_t)n * PS + (y + 1) * 82 + (x + 1)) * 128
        : ((size_t)n * HW + y * 80 + x) * 128;
#pragma unroll
    for (int ct = 0; ct < 2; ++ct) {
        const f32x16& acc = ct ? acc1 : acc0;
#pragma unroll
        for (int q = 0; q < 4; ++q) {
            const int co0 = ch * 64 + ct * 32 + 8 * q + 4 * lhalf;
            float v[4];
#pragma unroll
            for (int i = 0; i < 4; ++i) {
                float vv = acc[q * 4 + i] + bias[co0 + i];
                if (ACT == 1) vv = (vv >= 0.f) ? vv : 0.1f * vv;
                else vv = 10.f * tanhf(vv);
                v[i] = vv;
            }
            if (ACT == 1) {
                half4v hv = {(_Float16)v[0], (_Float16)v[1], (_Float16)v[2], (_Float16)v[3]};
                *(half4v*)((_Float16*)outp + rowbase + co0) = hv;
            } else {
                float4 fv = {v[0], v[1], v[2], v[3]};
                *(float4*)((float*)outp + rowbase + co0) = fv;
            }
        }
    }
}

// ---------------------------------------------------------------------------
// 1x1 conv (fp32 GEMM 128x128 over spatial). grid: (100, N), block 256.
// wt layout: [ci][128co].
// MODE 0: in fp32 NCHW  -> out v_s NHWC-16.
// MODE 1: in fp32 NHWC-16 ([n*8+hd][s][16]) -> out NCHW.
// ---------------------------------------------------------------------------
template <int MODE>
__global__ __launch_bounds__(256) void conv1x1_kernel(
    const float* __restrict__ in, const float* __restrict__ wt,
    const float* __restrict__ bias, float* __restrict__ out) {
    const int n = blockIdx.y;
    const int s0 = blockIdx.x * 64;
    const int t = threadIdx.x;
    const int sp_grp = t & 15;
    const int co_grp = t >> 4;

    __shared__ float Wl[16 * 128];
    __shared__ float Il[16 * 64];

    float acc[8][4];
#pragma unroll
    for (int i = 0; i < 8; ++i)
#pragma unroll
        for (int j = 0; j < 4; ++j) acc[i][j] = 0.f;

    for (int ch = 0; ch < 8; ++ch) {
        const int ci0 = ch * 16;
        __syncthreads();
        for (int i = t; i < 16 * 128; i += 256) Wl[i] = wt[ci0 * 128 + i];
        if (MODE == 0) {
            for (int i = t; i < 16 * 64; i += 256) {
                int ci = i >> 6, sp = i & 63;
                Il[i] = in[(size_t)(n * 128 + ci0 + ci) * HW + s0 + sp];
            }
        } else {
            int grp = t & 3, sp = t >> 2;
            const float4 v = *(const float4*)&in[(((size_t)(n * 8 + ch)) * HW + s0 + sp) * 16 + grp * 4];
            Il[(grp * 4 + 0) * 64 + sp] = v.x;
            Il[(grp * 4 + 1) * 64 + sp] = v.y;
            Il[(grp * 4 + 2) * 64 + sp] = v.z;
            Il[(grp * 4 + 3) * 64 + sp] = v.w;
        }
        __syncthreads();
#pragma unroll
        for (int ci = 0; ci < 16; ++ci) {
            float4 a0 = *(const float4*)&Wl[ci * 128 + co_grp * 8];
            float4 a1 = *(const float4*)&Wl[ci * 128 + co_grp * 8 + 4];
            float4 b  = *(const float4*)&Il[ci * 64 + sp_grp * 4];
            float av[8] = {a0.x, a0.y, a0.z, a0.w, a1.x, a1.y, a1.z, a1.w};
            float bv[4] = {b.x, b.y, b.z, b.w};
#pragma unroll
            for (int i = 0; i < 8; ++i)
#pragma unroll
                for (int j = 0; j < 4; ++j)
                    acc[i][j] = fmaf(av[i], bv[j], acc[i][j]);
        }
    }

#pragma unroll
    for (int i = 0; i < 8; ++i) {
        const int co = co_grp * 8 + i;
        const float bv = bias[co];
        if (MODE == 0) {
            const int hd = co >> 4, dd = co & 15;
#pragma unroll
            for (int j = 0; j < 4; ++j) {
                int s = s0 + sp_grp * 4 + j;
                out[((size_t)(n * 8 + hd) * HW + s) * 16 + dd] = acc[i][j] + bv;
            }
        } else {
#pragma unroll
            for (int j = 0; j < 4; ++j)
                out[(size_t)(n * 128 + co) * HW + s0 + sp_grp * 4 + j] = acc[i][j] + bv;
        }
    }
}

// ---------------------------------------------------------------------------
// Deformable attention, channel-vectorized + XCD-pinned slices.
// grid: (32 slices, 100 tiles), block 256 = 64 sites x 4 chgrp.
// v_s [nb][s][16] fp32; offs NHWC fp32; att NHWC-16 fp32.
// ---------------------------------------------------------------------------
__global__ __launch_bounds__(256) void deform_attn_kernel(
    const float* __restrict__ v_s, const float* __restrict__ offs,
    const float* __restrict__ ref, float* __restrict__ att) {
    const int slice = blockIdx.x;
    const int n = slice >> 3, hd = slice & 7;
    const int t = threadIdx.x;
    const int s = blockIdx.y * 64 + (t >> 2);
    const int d0 = (t & 3) * 4;
    const int nb = n * 8 + hd;

    const float4 cv = *(const float4*)&v_s[((size_t)nb * HW + s) * 16 + d0];
    const float rx = ref[(size_t)(n * HW + s) * 2 + 0] * 80.f - 0.5f;
    const float ry = ref[(size_t)(n * HW + s) * 2 + 1] * 80.f - 0.5f;

    const int e = (s >= 3200) ? 1 : 0;
    const float* ob0 = offs + ((size_t)n * HW + (2 * s - e * HW)) * 128 + hd * 16 + e;

    float4 sampled[8];
    float score[8];
#pragma unroll
    for (int p = 0; p < 8; ++p) {
        const float ox = ob0[2 * p];
        const float oy = ob0[128 + 2 * p];
        const float px = rx + ox;
        const float py = ry + oy;
        const float fx = floorf(px), fy = floorf(py);
        const int ix = (int)fx, iy = (int)fy;
        const float wx1 = px - fx, wy1 = py - fy;
        const float wx0 = 1.f - wx1, wy0 = 1.f - wy1;

        auto samp = [&](int xx, int yy) -> float4 {
            if (xx < 0 || xx >= Ww || yy < 0 || yy >= Hh) {
                float4 z = {0.f, 0.f, 0.f, 0.f};
                return z;
            }
            return *(const float4*)&v_s[((size_t)nb * HW + yy * Ww + xx) * 16 + d0];
        };
        const float4 v00 = samp(ix, iy);
        const float4 v01 = samp(ix + 1, iy);
        const float4 v10 = samp(ix, iy + 1);
        const float4 v11 = samp(ix + 1, iy + 1);
        const float w00 = wx0 * wy0, w01 = wx1 * wy0, w10 = wx0 * wy1, w11 = wx1 * wy1;
        float4 sv;
        sv.x = v00.x * w00 + v01.x * w01 + v10.x * w10 + v11.x * w11;
        sv.y = v00.y * w00 + v01.y * w01 + v10.y * w10 + v11.y * w11;
        sv.z = v00.z * w00 + v01.z * w01 + v10.z * w10 + v11.z * w11;
        sv.w = v00.w * w00 + v01.w * w01 + v10.w * w10 + v11.w * w11;
        sampled[p] = sv;
        float sc = sv.x * cv.x + sv.y * cv.y + sv.z * cv.z + sv.w * cv.w;
        sc += __shfl_xor(sc, 1);
        sc += __shfl_xor(sc, 2);
        score[p] = sc;
    }

    float m = score[0];
#pragma unroll
    for (int p = 1; p < 8; ++p) m = fmaxf(m, score[p]);
    float sum = 0.f, aw[8];
#pragma unroll
    for (int p = 0; p < 8; ++p) {
        aw[p] = __expf(score[p] - m);
        sum += aw[p];
    }
    const float inv = 1.f / sum;
    float4 o = {0.f, 0.f, 0.f, 0.f};
#pragma unroll
    for (int p = 0; p < 8; ++p) {
        o.x += aw[p] * sampled[p].x;
        o.y += aw[p] * sampled[p].y;
        o.z += aw[p] * sampled[p].z;
        o.w += aw[p] * sampled[p].w;
    }
    o.x *= inv; o.y *= inv; o.z *= inv; o.w *= inv;

    *(float4*)&att[((size_t)nb * HW + s) * 16 + d0] = o;
}

// ---------------------------------------------------------------------------
extern "C" void kernel_launch(void* const* d_in, const int* in_sizes, int n_in,
                              void* d_out, int out_size, void* d_ws, size_t ws_size,
                              hipStream_t stream) {
    const float* query = (const float*)d_in[0];
    const float* value = (const float*)d_in[1];
    const float* ref   = (const float*)d_in[2];
    const float* co_w1 = (const float*)d_in[3];
    const float* co_b1 = (const float*)d_in[4];
    const float* co_w2 = (const float*)d_in[5];
    const float* co_b2 = (const float*)d_in[6];
    const float* co_w3 = (const float*)d_in[7];
    const float* co_b3 = (const float*)d_in[8];
    const float* co_w4 = (const float*)d_in[9];
    const float* co_b4 = (const float*)d_in[10];
    const float* val_w = (const float*)d_in[11];
    const float* val_b = (const float*)d_in[12];
    const float* out_w = (const float*)d_in[13];
    const float* out_b = (const float*)d_in[14];

    char* ws = (char*)d_ws;
    size_t o = 0;
    auto alloc = [&](size_t bytes) { char* p = ws + o; o += (bytes + 255) & ~(size_t)255; return p; };

    _Float16* wb2 = (_Float16*)alloc(147456 * 2);
    _Float16* wb3 = (_Float16*)alloc(147456 * 2);
    _Float16* wb4 = (_Float16*)alloc(147456 * 2);
    float* wtv = (float*)alloc(16384 * 4);
    float* wto = (float*)alloc(16384 * 4);
    char* vsR = alloc(3276800 * 4);            // v_s fp32 [32][6400][16]
    float* v_s = (float*)vsR;
    _Float16* wb1 = (_Float16*)vsR;            // alias: wb1 dead before v_s written
    char* R1 = alloc((size_t)NB * PS * 256 * 2);  // 13.77 MB
    _Float16* q_h = (_Float16*)R1;             // fp16 padded NHWC [4][6724][256]
    float* o4 = (float*)R1;                    // fp32 NHWC [4][6400][128]; q_h dead
    char* R2 = alloc((size_t)NB * PS * 128 * 2 * 2);  // 13.78 MB
    _Float16* hA = (_Float16*)R2;              // fp16 padded NHWC [4][6724][128]
    _Float16* hB = (_Float16*)(R2 + (size_t)NB * PS * 128 * 2);
    float* att = (float*)R2;                   // NHWC-16 fp32; used after hA/hB dead

    // fused prep: wblobs + 1x1 transposes + pad zeroing
    prep_kernel<<<4304, 256, 0, stream>>>(co_w1, co_w2, co_w3, co_w4, val_w, out_w,
                                          wb1, wb2, wb3, wb4, wtv, wto,
                                          (int*)q_h, (int*)hA, (int*)hB);

    // transpose query to fp16 padded NHWC (XCD-pinned like consumers)
    q_transpose<<<400, 256, 0, stream>>>(query, q_h);

    // conv1 (must precede val-conv: wb1 aliases v_s region)
    conv3x3_mfma<256, 1><<<1600, 64, 0, stream>>>(q_h, wb1, co_b1, hA);

    // v = 1x1 conv(value) -> v_s (NHWC-16 fp32)
    conv1x1_kernel<0><<<dim3(100, NB), 256, 0, stream>>>(value, wtv, val_b, v_s);

    // rest of offset conv stack
    conv3x3_mfma<128, 1><<<1600, 64, 0, stream>>>(hA, wb2, co_b2, hB);
    conv3x3_mfma<128, 1><<<1600, 64, 0, stream>>>(hB, wb3, co_b3, hA);
    conv3x3_mfma<128, 2><<<1600, 64, 0, stream>>>(hA, wb4, co_b4, o4);

    // deformable attention -> att (NHWC-16 fp32), XCD-pinned slices
    deform_attn_kernel<<<dim3(32, 100), 256, 0, stream>>>(v_s, o4, ref, att);

    // final 1x1 conv -> d_out (NCHW fp32)
    conv1x1_kernel<1><<<dim3(100, NB), 256, 0, stream>>>(att, wto, out_b, (float*)d_out);
}

// Round 9
// 313.366 us; speedup vs baseline: 1.1412x; 1.0759x over previous
//
#include <hip/hip_runtime.h>
#include <math.h>

#define Hh 80
#define Ww 80
#define HW 6400
#define PS 6724      // 82*82 padded spatial
#define NB 4

typedef _Float16 half8 __attribute__((ext_vector_type(8)));
typedef _Float16 half4v __attribute__((ext_vector_type(4)));
typedef float f32x16 __attribute__((ext_vector_type(16)));

// ---------------------------------------------------------------------------
// Fused prep: 4 MFMA A-blobs (fp16) + 2 1x1 transposes + pad-zeroing of the
// chunked-planar activation buffers ([n][c][82x82][32], 324 border sites).
// wblob: flat = (CT*NS + c*18 + tap*2 + h)*512 + lane*8 + j
//   co = CT*32 + (lane&31);  ci = c*32 + h*16 + (lane>>5)*8 + j
// ---------------------------------------------------------------------------
__device__ inline void wblob_one(const float* src, _Float16* dst, int CI, int d) {
    int NC = CI / 32;
    int j = d & 7;
    int l = (d >> 3) & 63;
    int h = (d >> 9) & 1;
    int rest = d >> 10;
    int tap = rest % 9;
    rest /= 9;
    int c = rest % NC;
    int CT = rest / NC;
    int co = CT * 32 + (l & 31);
    int ci = c * 32 + h * 16 + (l >> 5) * 8 + j;
    dst[d] = (_Float16)src[((size_t)co * CI + ci) * 9 + tap];
}

__device__ inline int padsite(int p) {
    if (p < 82) return p;                       // row 0
    if (p < 164) return 81 * 82 + (p - 82);     // row 81
    if (p < 244) return (p - 163) * 82;         // col 0, rows 1..80
    return (p - 243) * 82 + 81;                 // col 81, rows 1..80
}

__global__ void prep_kernel(const float* __restrict__ w1, const float* __restrict__ w2,
                            const float* __restrict__ w3, const float* __restrict__ w4,
                            const float* __restrict__ vw, const float* __restrict__ ow,
                            _Float16* __restrict__ b1, _Float16* __restrict__ b2,
                            _Float16* __restrict__ b3, _Float16* __restrict__ b4,
                            float* __restrict__ tv, float* __restrict__ to,
                            int* __restrict__ qh_i, int* __restrict__ hA_i,
                            int* __restrict__ hB_i) {
    int idx = blockIdx.x * 256 + threadIdx.x;
    if (idx < 294912) { wblob_one(w1, b1, 256, idx); return; }
    idx -= 294912;
    if (idx < 147456) { wblob_one(w2, b2, 128, idx); return; }
    idx -= 147456;
    if (idx < 147456) { wblob_one(w3, b3, 128, idx); return; }
    idx -= 147456;
    if (idx < 147456) { wblob_one(w4, b4, 128, idx); return; }
    idx -= 147456;
    if (idx < 16384) { int co = idx & 127, ci = idx >> 7; tv[idx] = vw[co * 128 + ci]; return; }
    idx -= 16384;
    if (idx < 16384) { int co = idx & 127, ci = idx >> 7; to[idx] = ow[co * 128 + ci]; return; }
    idx -= 16384;
    if (idx < 165888) {  // q_h pads: 4n x 8c x 324 sites x 16 ints (32 halfs)
        int n = idx / 41472, rr = idx % 41472;
        int c = rr / 5184, r2 = rr % 5184;
        int p = r2 >> 4, k = r2 & 15;
        qh_i[((size_t)(n * 8 + c) * PS + padsite(p)) * 16 + k] = 0;
        return;
    }
    idx -= 165888;
    if (idx < 82944) {   // hA pads: 4n x 4c x 324 x 16 ints
        int n = idx / 20736, rr = idx % 20736;
        int c = rr / 5184, r2 = rr % 5184;
        int p = r2 >> 4, k = r2 & 15;
        hA_i[((size_t)(n * 4 + c) * PS + padsite(p)) * 16 + k] = 0;
        return;
    }
    idx -= 82944;
    if (idx < 82944) {
        int n = idx / 20736, rr = idx % 20736;
        int c = rr / 5184, r2 = rr % 5184;
        int p = r2 >> 4, k = r2 & 15;
        hB_i[((size_t)(n * 4 + c) * PS + padsite(p)) * 16 + k] = 0;
    }
}

// ---------------------------------------------------------------------------
// query fp32 NCHW -> fp16 chunked-planar [n][8c][82x82][32], XCD-pinned.
// grid (400), block 256: xcd = b&7 -> (n = xcd&3, half = xcd>>2).
// ---------------------------------------------------------------------------
__global__ __launch_bounds__(256) void q_transpose(
    const float* __restrict__ in, _Float16* __restrict__ out) {
    const int b = blockIdx.x;
    const int xcd = b & 7, n = xcd & 3, hi = xcd >> 2;
    const int s0 = hi * 3200 + (b >> 3) * 64;
    const int t = threadIdx.x;
    constexpr int CI = 256, ST = CI + 8;
    __shared__ _Float16 T[64 * ST];
    for (int idx = t; idx < 64 * CI; idx += 256) {
        int ci = idx >> 6, sl = idx & 63;
        T[sl * ST + ci] = (_Float16)in[((size_t)n * CI + ci) * HW + s0 + sl];
    }
    __syncthreads();
    for (int idx = t; idx < 64 * 32; idx += 256) {
        int q = idx & 31, sl = idx >> 5;
        int s = s0 + sl, yy = s / 80, xx = s % 80;
        int c = q >> 2, off = (q & 3) * 8;
        *(int4*)(out + ((size_t)(n * 8 + c) * PS + (yy + 1) * 82 + (xx + 1)) * 32 + off) =
            *(const int4*)(&T[sl * ST + q * 8]);
    }
}

// ---------------------------------------------------------------------------
// MFMA implicit-GEMM 3x3 conv, pad=1, chunked-planar fp16 in ([n][c][82x82][32]).
// Barrier-free, no LDS, XCD-pinned. Block = 256 thr = 4 waves sharing ONE
// co-half (A stream identical across waves -> L1-served) over a 16x8 region;
// wave = 64co x 32sp (8x4). Depth-9 rotating register pipeline.
// grid: flat (400). b&7 -> XCD -> (n, image-half); b>>3 -> (coH, region).
// ACT 1: leaky -> chunked-planar fp16 [n][4c][PS][32].
// ACT 2: 10*tanh -> fp32 NHWC [n][6400][128].
// ---------------------------------------------------------------------------
template <int NCp, int ACT>
__global__ __launch_bounds__(256) void conv3x3_mfma(
    const _Float16* __restrict__ in, const _Float16* __restrict__ wblob,
    const float* __restrict__ bias, void* __restrict__ outp) {
    constexpr int NS = NCp * 18;
    const int b = blockIdx.x;
    const int xcd = b & 7, n = xcd & 3, hi = xcd >> 2;
    const int r = b >> 3;                    // 0..49
    const int coH = r & 1, j = r >> 1;       // j in [0,25)
    const int x0 = (j % 5) * 16, y0 = hi * 40 + (j / 5) * 8;
    const int t = threadIdx.x;
    const int w = t >> 6, l = t & 63;
    const int x0w = x0 + (w & 1) * 8, y0w = y0 + (w >> 1) * 4;
    const int lane31 = l & 31, lhalf = l >> 5;
    const int lx = lane31 & 7, ly = lane31 >> 3;

    const _Float16* p0 = in + ((size_t)(n * NCp) * PS + (y0w + ly + 1) * 82 + (x0w + lx + 1)) * 32 + lhalf * 8;
    const _Float16* wA0 = wblob + ((size_t)(coH * 2) * NS) * 512 + l * 8;
    const _Float16* wA1 = wA0 + (size_t)NS * 512;

    f32x16 acc0 = {}, acc1 = {};
    half8 bB[9], bA0[9], bA1[9];

    // element offset of K-step t2 in the B (activation) stream
    auto boff = [](int t2) -> size_t {
        int c = t2 / 18, u = t2 % 18;
        int tap = u >> 1, h = u & 1;
        int dy = tap / 3, dx = tap % 3;
        return (size_t)c * (PS * 32) + ((dy - 1) * 82 + (dx - 1)) * 32 + h * 16;
    };

#pragma unroll
    for (int t2 = 0; t2 < 9; ++t2) {
        bB[t2]  = *(const half8*)(p0 + boff(t2));
        bA0[t2] = *(const half8*)(wA0 + t2 * 512);
        bA1[t2] = *(const half8*)(wA1 + t2 * 512);
    }

#pragma unroll
    for (int t2 = 0; t2 < NS; ++t2) {
        const int slot = t2 % 9;
        acc0 = __builtin_amdgcn_mfma_f32_32x32x16_f16(bA0[slot], bB[slot], acc0, 0, 0, 0);
        acc1 = __builtin_amdgcn_mfma_f32_32x32x16_f16(bA1[slot], bB[slot], acc1, 0, 0, 0);
        if (t2 + 9 < NS) {
            const int t2p = t2 + 9;
            bB[slot]  = *(const half8*)(p0 + boff(t2p));
            bA0[slot] = *(const half8*)(wA0 + (size_t)t2p * 512);
            bA1[slot] = *(const half8*)(wA1 + (size_t)t2p * 512);
        }
    }

    // epilogue: D col(site)=lane&31, row(co)=(reg&3)+8*(reg>>2)+4*(lane>>5)
    const int y = y0w + ly, x = x0w + lx;
#pragma unroll
    for (int ct = 0; ct < 2; ++ct) {
        const f32x16& acc = ct ? acc1 : acc0;
#pragma unroll
        for (int q = 0; q < 4; ++q) {
            const int inner = 8 * q + 4 * lhalf;
            const int co0 = coH * 64 + ct * 32 + inner;
            float v[4];
#pragma unroll
            for (int i = 0; i < 4; ++i) {
                float vv = acc[q * 4 + i] + bias[co0 + i];
                if (ACT == 1) vv = (vv >= 0.f) ? vv : 0.1f * vv;
                else vv = 10.f * tanhf(vv);
                v[i] = vv;
            }
            if (ACT == 1) {
                half4v hv = {(_Float16)v[0], (_Float16)v[1], (_Float16)v[2], (_Float16)v[3]};
                const int c2 = coH * 2 + ct;
                *(half4v*)((_Float16*)outp +
                    ((size_t)(n * 4 + c2) * PS + (y + 1) * 82 + (x + 1)) * 32 + inner) = hv;
            } else {
                float4 fv = {v[0], v[1], v[2], v[3]};
                *(float4*)((float*)outp + ((size_t)n * HW + y * 80 + x) * 128 + co0) = fv;
            }
        }
    }
}

// ---------------------------------------------------------------------------
// 1x1 conv (fp32 GEMM 128x128 over spatial). grid: (100, N), block 256.
// wt layout: [ci][128co].
// MODE 0: in fp32 NCHW  -> out v_s NHWC-16.
// MODE 1: in fp32 NHWC-16 ([n*8+hd][s][16]) -> out NCHW.
// ---------------------------------------------------------------------------
template <int MODE>
__global__ __launch_bounds__(256) void conv1x1_kernel(
    const float* __restrict__ in, const float* __restrict__ wt,
    const float* __restrict__ bias, float* __restrict__ out) {
    const int n = blockIdx.y;
    const int s0 = blockIdx.x * 64;
    const int t = threadIdx.x;
    const int sp_grp = t & 15;
    const int co_grp = t >> 4;

    __shared__ float Wl[16 * 128];
    __shared__ float Il[16 * 64];

    float acc[8][4];
#pragma unroll
    for (int i = 0; i < 8; ++i)
#pragma unroll
        for (int j = 0; j < 4; ++j) acc[i][j] = 0.f;

    for (int ch = 0; ch < 8; ++ch) {
        const int ci0 = ch * 16;
        __syncthreads();
        for (int i = t; i < 16 * 128; i += 256) Wl[i] = wt[ci0 * 128 + i];
        if (MODE == 0) {
            for (int i = t; i < 16 * 64; i += 256) {
                int ci = i >> 6, sp = i & 63;
                Il[i] = in[(size_t)(n * 128 + ci0 + ci) * HW + s0 + sp];
            }
        } else {
            int grp = t & 3, sp = t >> 2;
            const float4 v = *(const float4*)&in[(((size_t)(n * 8 + ch)) * HW + s0 + sp) * 16 + grp * 4];
            Il[(grp * 4 + 0) * 64 + sp] = v.x;
            Il[(grp * 4 + 1) * 64 + sp] = v.y;
            Il[(grp * 4 + 2) * 64 + sp] = v.z;
            Il[(grp * 4 + 3) * 64 + sp] = v.w;
        }
        __syncthreads();
#pragma unroll
        for (int ci = 0; ci < 16; ++ci) {
            float4 a0 = *(const float4*)&Wl[ci * 128 + co_grp * 8];
            float4 a1 = *(const float4*)&Wl[ci * 128 + co_grp * 8 + 4];
            float4 b  = *(const float4*)&Il[ci * 64 + sp_grp * 4];
            float av[8] = {a0.x, a0.y, a0.z, a0.w, a1.x, a1.y, a1.z, a1.w};
            float bv[4] = {b.x, b.y, b.z, b.w};
#pragma unroll
            for (int i = 0; i < 8; ++i)
#pragma unroll
                for (int j = 0; j < 4; ++j)
                    acc[i][j] = fmaf(av[i], bv[j], acc[i][j]);
        }
    }

#pragma unroll
    for (int i = 0; i < 8; ++i) {
        const int co = co_grp * 8 + i;
        const float bv = bias[co];
        if (MODE == 0) {
            const int hd = co >> 4, dd = co & 15;
#pragma unroll
            for (int j = 0; j < 4; ++j) {
                int s = s0 + sp_grp * 4 + j;
                out[((size_t)(n * 8 + hd) * HW + s) * 16 + dd] = acc[i][j] + bv;
            }
        } else {
#pragma unroll
            for (int j = 0; j < 4; ++j)
                out[(size_t)(n * 128 + co) * HW + s0 + sp_grp * 4 + j] = acc[i][j] + bv;
        }
    }
}

// ---------------------------------------------------------------------------
// Deformable attention, channel-vectorized + XCD-pinned slices.
// grid: (32 slices, 100 tiles), block 256 = 64 sites x 4 chgrp.
// v_s [nb][s][16] fp32; offs NHWC fp32; att NHWC-16 fp32.
// ---------------------------------------------------------------------------
__global__ __launch_bounds__(256) void deform_attn_kernel(
    const float* __restrict__ v_s, const float* __restrict__ offs,
    const float* __restrict__ ref, float* __restrict__ att) {
    const int slice = blockIdx.x;
    const int n = slice >> 3, hd = slice & 7;
    const int t = threadIdx.x;
    const int s = blockIdx.y * 64 + (t >> 2);
    const int d0 = (t & 3) * 4;
    const int nb = n * 8 + hd;

    const float4 cv = *(const float4*)&v_s[((size_t)nb * HW + s) * 16 + d0];
    const float rx = ref[(size_t)(n * HW + s) * 2 + 0] * 80.f - 0.5f;
    const float ry = ref[(size_t)(n * HW + s) * 2 + 1] * 80.f - 0.5f;

    const int e = (s >= 3200) ? 1 : 0;
    const float* ob0 = offs + ((size_t)n * HW + (2 * s - e * HW)) * 128 + hd * 16 + e;

    float4 sampled[8];
    float score[8];
#pragma unroll
    for (int p = 0; p < 8; ++p) {
        const float ox = ob0[2 * p];
        const float oy = ob0[128 + 2 * p];
        const float px = rx + ox;
        const float py = ry + oy;
        const float fx = floorf(px), fy = floorf(py);
        const int ix = (int)fx, iy = (int)fy;
        const float wx1 = px - fx, wy1 = py - fy;
        const float wx0 = 1.f - wx1, wy0 = 1.f - wy1;

        auto samp = [&](int xx, int yy) -> float4 {
            if (xx < 0 || xx >= Ww || yy < 0 || yy >= Hh) {
                float4 z = {0.f, 0.f, 0.f, 0.f};
                return z;
            }
            return *(const float4*)&v_s[((size_t)nb * HW + yy * Ww + xx) * 16 + d0];
        };
        const float4 v00 = samp(ix, iy);
        const float4 v01 = samp(ix + 1, iy);
        const float4 v10 = samp(ix, iy + 1);
        const float4 v11 = samp(ix + 1, iy + 1);
        const float w00 = wx0 * wy0, w01 = wx1 * wy0, w10 = wx0 * wy1, w11 = wx1 * wy1;
        float4 sv;
        sv.x = v00.x * w00 + v01.x * w01 + v10.x * w10 + v11.x * w11;
        sv.y = v00.y * w00 + v01.y * w01 + v10.y * w10 + v11.y * w11;
        sv.z = v00.z * w00 + v01.z * w01 + v10.z * w10 + v11.z * w11;
        sv.w = v00.w * w00 + v01.w * w01 + v10.w * w10 + v11.w * w11;
        sampled[p] = sv;
        float sc = sv.x * cv.x + sv.y * cv.y + sv.z * cv.z + sv.w * cv.w;
        sc += __shfl_xor(sc, 1);
        sc += __shfl_xor(sc, 2);
        score[p] = sc;
    }

    float m = score[0];
#pragma unroll
    for (int p = 1; p < 8; ++p) m = fmaxf(m, score[p]);
    float sum = 0.f, aw[8];
#pragma unroll
    for (int p = 0; p < 8; ++p) {
        aw[p] = __expf(score[p] - m);
        sum += aw[p];
    }
    const float inv = 1.f / sum;
    float4 o = {0.f, 0.f, 0.f, 0.f};
#pragma unroll
    for (int p = 0; p < 8; ++p) {
        o.x += aw[p] * sampled[p].x;
        o.y += aw[p] * sampled[p].y;
        o.z += aw[p] * sampled[p].z;
        o.w += aw[p] * sampled[p].w;
    }
    o.x *= inv; o.y *= inv; o.z *= inv; o.w *= inv;

    *(float4*)&att[((size_t)nb * HW + s) * 16 + d0] = o;
}

// ---------------------------------------------------------------------------
extern "C" void kernel_launch(void* const* d_in, const int* in_sizes, int n_in,
                              void* d_out, int out_size, void* d_ws, size_t ws_size,
                              hipStream_t stream) {
    const float* query = (const float*)d_in[0];
    const float* value = (const float*)d_in[1];
    const float* ref   = (const float*)d_in[2];
    const float* co_w1 = (const float*)d_in[3];
    const float* co_b1 = (const float*)d_in[4];
    const float* co_w2 = (const float*)d_in[5];
    const float* co_b2 = (const float*)d_in[6];
    const float* co_w3 = (const float*)d_in[7];
    const float* co_b3 = (const float*)d_in[8];
    const float* co_w4 = (const float*)d_in[9];
    const float* co_b4 = (const float*)d_in[10];
    const float* val_w = (const float*)d_in[11];
    const float* val_b = (const float*)d_in[12];
    const float* out_w = (const float*)d_in[13];
    const float* out_b = (const float*)d_in[14];

    char* ws = (char*)d_ws;
    size_t o = 0;
    auto alloc = [&](size_t bytes) { char* p = ws + o; o += (bytes + 255) & ~(size_t)255; return p; };

    _Float16* wb2 = (_Float16*)alloc(147456 * 2);
    _Float16* wb3 = (_Float16*)alloc(147456 * 2);
    _Float16* wb4 = (_Float16*)alloc(147456 * 2);
    float* wtv = (float*)alloc(16384 * 4);
    float* wto = (float*)alloc(16384 * 4);
    char* vsR = alloc(3276800 * 4);            // v_s fp32 [32][6400][16]
    float* v_s = (float*)vsR;
    _Float16* wb1 = (_Float16*)vsR;            // alias: wb1 dead before v_s written
    char* R1 = alloc((size_t)NB * 8 * PS * 32 * 2);  // 13.77 MB
    _Float16* q_h = (_Float16*)R1;             // fp16 planar [4][8][PS][32]
    float* o4 = (float*)R1;                    // fp32 NHWC [4][6400][128]; q_h dead
    char* R2 = alloc((size_t)NB * 4 * PS * 32 * 2 * 2);  // 13.78 MB
    _Float16* hA = (_Float16*)R2;              // fp16 planar [4][4][PS][32]
    _Float16* hB = (_Float16*)(R2 + (size_t)NB * 4 * PS * 32 * 2);
    float* att = (float*)R2;                   // NHWC-16 fp32; used after hA/hB dead

    // fused prep: wblobs + 1x1 transposes + pad zeroing
    prep_kernel<<<4304, 256, 0, stream>>>(co_w1, co_w2, co_w3, co_w4, val_w, out_w,
                                          wb1, wb2, wb3, wb4, wtv, wto,
                                          (int*)q_h, (int*)hA, (int*)hB);

    // transpose query to chunked-planar fp16 (XCD-pinned like consumers)
    q_transpose<<<400, 256, 0, stream>>>(query, q_h);

    // conv1 (must precede val-conv: wb1 aliases v_s region)
    conv3x3_mfma<8, 1><<<400, 256, 0, stream>>>(q_h, wb1, co_b1, hA);

    // v = 1x1 conv(value) -> v_s (NHWC-16 fp32)
    conv1x1_kernel<0><<<dim3(100, NB), 256, 0, stream>>>(value, wtv, val_b, v_s);

    // rest of offset conv stack
    conv3x3_mfma<4, 1><<<400, 256, 0, stream>>>(hA, wb2, co_b2, hB);
    conv3x3_mfma<4, 1><<<400, 256, 0, stream>>>(hB, wb3, co_b3, hA);
    conv3x3_mfma<4, 2><<<400, 256, 0, stream>>>(hA, wb4, co_b4, o4);

    // deformable attention -> att (NHWC-16 fp32), XCD-pinned slices
    deform_attn_kernel<<<dim3(32, 100), 256, 0, stream>>>(v_s, o4, ref, att);

    // final 1x1 conv -> d_out (NCHW fp32)
    conv1x1_kernel<1><<<dim3(100, NB), 256, 0, stream>>>(att, wto, out_b, (float*)d_out);
}

// Round 10
// 299.754 us; speedup vs baseline: 1.1930x; 1.0454x over previous
//
#include <hip/hip_runtime.h>
#include <math.h>

#define Hh 80
#define Ww 80
#define HW 6400
#define PS 6724      // 82*82 padded spatial
#define NB 4

typedef _Float16 half8 __attribute__((ext_vector_type(8)));
typedef _Float16 half4v __attribute__((ext_vector_type(4)));
typedef float f32x16 __attribute__((ext_vector_type(16)));

// ---------------------------------------------------------------------------
// Fused prep: 4 MFMA A-blobs (fp16) + 2 1x1 transposes + pad-zeroing of the
// chunked-planar activation buffers ([n][c][82x82][32], 324 border sites).
// wblob: flat = (CT*NS + c*18 + tap*2 + h)*512 + lane*8 + j
//   co = CT*32 + (lane&31);  ci = c*32 + h*16 + (lane>>5)*8 + j
// ---------------------------------------------------------------------------
__device__ inline void wblob_one(const float* src, _Float16* dst, int CI, int d) {
    int NC = CI / 32;
    int j = d & 7;
    int l = (d >> 3) & 63;
    int h = (d >> 9) & 1;
    int rest = d >> 10;
    int tap = rest % 9;
    rest /= 9;
    int c = rest % NC;
    int CT = rest / NC;
    int co = CT * 32 + (l & 31);
    int ci = c * 32 + h * 16 + (l >> 5) * 8 + j;
    dst[d] = (_Float16)src[((size_t)co * CI + ci) * 9 + tap];
}

__device__ inline int padsite(int p) {
    if (p < 82) return p;                       // row 0
    if (p < 164) return 81 * 82 + (p - 82);     // row 81
    if (p < 244) return (p - 163) * 82;         // col 0, rows 1..80
    return (p - 243) * 82 + 81;                 // col 81, rows 1..80
}

__global__ void prep_kernel(const float* __restrict__ w1, const float* __restrict__ w2,
                            const float* __restrict__ w3, const float* __restrict__ w4,
                            const float* __restrict__ vw, const float* __restrict__ ow,
                            _Float16* __restrict__ b1, _Float16* __restrict__ b2,
                            _Float16* __restrict__ b3, _Float16* __restrict__ b4,
                            float* __restrict__ tv, float* __restrict__ to,
                            int* __restrict__ qh_i, int* __restrict__ hA_i,
                            int* __restrict__ hB_i) {
    int idx = blockIdx.x * 256 + threadIdx.x;
    if (idx < 294912) { wblob_one(w1, b1, 256, idx); return; }
    idx -= 294912;
    if (idx < 147456) { wblob_one(w2, b2, 128, idx); return; }
    idx -= 147456;
    if (idx < 147456) { wblob_one(w3, b3, 128, idx); return; }
    idx -= 147456;
    if (idx < 147456) { wblob_one(w4, b4, 128, idx); return; }
    idx -= 147456;
    if (idx < 16384) { int co = idx & 127, ci = idx >> 7; tv[idx] = vw[co * 128 + ci]; return; }
    idx -= 16384;
    if (idx < 16384) { int co = idx & 127, ci = idx >> 7; to[idx] = ow[co * 128 + ci]; return; }
    idx -= 16384;
    if (idx < 165888) {  // q_h pads: 4n x 8c x 324 sites x 16 ints (32 halfs)
        int n = idx / 41472, rr = idx % 41472;
        int c = rr / 5184, r2 = rr % 5184;
        int p = r2 >> 4, k = r2 & 15;
        qh_i[((size_t)(n * 8 + c) * PS + padsite(p)) * 16 + k] = 0;
        return;
    }
    idx -= 165888;
    if (idx < 82944) {   // hA pads: 4n x 4c x 324 x 16 ints
        int n = idx / 20736, rr = idx % 20736;
        int c = rr / 5184, r2 = rr % 5184;
        int p = r2 >> 4, k = r2 & 15;
        hA_i[((size_t)(n * 4 + c) * PS + padsite(p)) * 16 + k] = 0;
        return;
    }
    idx -= 82944;
    if (idx < 82944) {
        int n = idx / 20736, rr = idx % 20736;
        int c = rr / 5184, r2 = rr % 5184;
        int p = r2 >> 4, k = r2 & 15;
        hB_i[((size_t)(n * 4 + c) * PS + padsite(p)) * 16 + k] = 0;
    }
}

// ---------------------------------------------------------------------------
// query fp32 NCHW -> fp16 chunked-planar [n][8c][82x82][32], XCD-pinned.
// grid (400), block 256: xcd = b&7 -> (n = xcd&3, half = xcd>>2).
// ---------------------------------------------------------------------------
__global__ __launch_bounds__(256) void q_transpose(
    const float* __restrict__ in, _Float16* __restrict__ out) {
    const int b = blockIdx.x;
    const int xcd = b & 7, n = xcd & 3, hi = xcd >> 2;
    const int s0 = hi * 3200 + (b >> 3) * 64;
    const int t = threadIdx.x;
    constexpr int CI = 256, ST = CI + 8;
    __shared__ _Float16 T[64 * ST];
    for (int idx = t; idx < 64 * CI; idx += 256) {
        int ci = idx >> 6, sl = idx & 63;
        T[sl * ST + ci] = (_Float16)in[((size_t)n * CI + ci) * HW + s0 + sl];
    }
    __syncthreads();
    for (int idx = t; idx < 64 * 32; idx += 256) {
        int q = idx & 31, sl = idx >> 5;
        int s = s0 + sl, yy = s / 80, xx = s % 80;
        int c = q >> 2, off = (q & 3) * 8;
        *(int4*)(out + ((size_t)(n * 8 + c) * PS + (yy + 1) * 82 + (xx + 1)) * 32 + off) =
            *(const int4*)(&T[sl * ST + q * 8]);
    }
}

// ---------------------------------------------------------------------------
// MFMA implicit-GEMM 3x3 conv, pad=1, chunked-planar fp16 in ([n][c][82x82][32]).
// Barrier-free, no LDS, XCD-pinned. Block = 256 thr = 4 waves sharing ONE
// co-half (A stream identical across waves -> L1-served) over a 16x8 region;
// wave = 64co x 32sp (8x4). Depth-9 rotating register pipeline.
// grid: flat (400). b&7 -> XCD -> (n, image-half); b>>3 -> (coH, region).
// ACT 1: leaky -> chunked-planar fp16 [n][4c][PS][32].
// ACT 2: 10*tanh -> fp32 NHWC [n][6400][128].
// ---------------------------------------------------------------------------
template <int NCp, int ACT>
__global__ __launch_bounds__(256) void conv3x3_mfma(
    const _Float16* __restrict__ in, const _Float16* __restrict__ wblob,
    const float* __restrict__ bias, void* __restrict__ outp) {
    constexpr int NS = NCp * 18;
    const int b = blockIdx.x;
    const int xcd = b & 7, n = xcd & 3, hi = xcd >> 2;
    const int r = b >> 3;                    // 0..49
    const int coH = r & 1, j = r >> 1;       // j in [0,25)
    const int x0 = (j % 5) * 16, y0 = hi * 40 + (j / 5) * 8;
    const int t = threadIdx.x;
    const int w = t >> 6, l = t & 63;
    const int x0w = x0 + (w & 1) * 8, y0w = y0 + (w >> 1) * 4;
    const int lane31 = l & 31, lhalf = l >> 5;
    const int lx = lane31 & 7, ly = lane31 >> 3;

    const _Float16* p0 = in + ((size_t)(n * NCp) * PS + (y0w + ly + 1) * 82 + (x0w + lx + 1)) * 32 + lhalf * 8;
    const _Float16* wA0 = wblob + ((size_t)(coH * 2) * NS) * 512 + l * 8;
    const _Float16* wA1 = wA0 + (size_t)NS * 512;

    f32x16 acc0 = {}, acc1 = {};
    half8 bB[9], bA0[9], bA1[9];

    // element offset of K-step t2 in the B (activation) stream
    auto boff = [](int t2) -> size_t {
        int c = t2 / 18, u = t2 % 18;
        int tap = u >> 1, h = u & 1;
        int dy = tap / 3, dx = tap % 3;
        return (size_t)c * (PS * 32) + ((dy - 1) * 82 + (dx - 1)) * 32 + h * 16;
    };

#pragma unroll
    for (int t2 = 0; t2 < 9; ++t2) {
        bB[t2]  = *(const half8*)(p0 + boff(t2));
        bA0[t2] = *(const half8*)(wA0 + t2 * 512);
        bA1[t2] = *(const half8*)(wA1 + t2 * 512);
    }

#pragma unroll
    for (int t2 = 0; t2 < NS; ++t2) {
        const int slot = t2 % 9;
        acc0 = __builtin_amdgcn_mfma_f32_32x32x16_f16(bA0[slot], bB[slot], acc0, 0, 0, 0);
        acc1 = __builtin_amdgcn_mfma_f32_32x32x16_f16(bA1[slot], bB[slot], acc1, 0, 0, 0);
        if (t2 + 9 < NS) {
            const int t2p = t2 + 9;
            bB[slot]  = *(const half8*)(p0 + boff(t2p));
            bA0[slot] = *(const half8*)(wA0 + (size_t)t2p * 512);
            bA1[slot] = *(const half8*)(wA1 + (size_t)t2p * 512);
        }
    }

    // epilogue: D col(site)=lane&31, row(co)=(reg&3)+8*(reg>>2)+4*(lane>>5)
    const int y = y0w + ly, x = x0w + lx;
#pragma unroll
    for (int ct = 0; ct < 2; ++ct) {
        const f32x16& acc = ct ? acc1 : acc0;
#pragma unroll
        for (int q = 0; q < 4; ++q) {
            const int inner = 8 * q + 4 * lhalf;
            const int co0 = coH * 64 + ct * 32 + inner;
            float v[4];
#pragma unroll
            for (int i = 0; i < 4; ++i) {
                float vv = acc[q * 4 + i] + bias[co0 + i];
                if (ACT == 1) vv = (vv >= 0.f) ? vv : 0.1f * vv;
                else vv = 10.f * tanhf(vv);
                v[i] = vv;
            }
            if (ACT == 1) {
                half4v hv = {(_Float16)v[0], (_Float16)v[1], (_Float16)v[2], (_Float16)v[3]};
                const int c2 = coH * 2 + ct;
                *(half4v*)((_Float16*)outp +
                    ((size_t)(n * 4 + c2) * PS + (y + 1) * 82 + (x + 1)) * 32 + inner) = hv;
            } else {
                float4 fv = {v[0], v[1], v[2], v[3]};
                *(float4*)((float*)outp + ((size_t)n * HW + y * 80 + x) * 128 + co0) = fv;
            }
        }
    }
}

// ---------------------------------------------------------------------------
// 1x1 conv (fp32 GEMM 128x128 over spatial). grid: (100, N), block 256.
// wt layout: [ci][128co].
// MODE 0: in fp32 NCHW  -> out v_s NHWC-16.
// MODE 1: in fp32 NHWC-16 ([n*8+hd][s][16]) -> out NCHW.
// ---------------------------------------------------------------------------
template <int MODE>
__global__ __launch_bounds__(256) void conv1x1_kernel(
    const float* __restrict__ in, const float* __restrict__ wt,
    const float* __restrict__ bias, float* __restrict__ out) {
    const int n = blockIdx.y;
    const int s0 = blockIdx.x * 64;
    const int t = threadIdx.x;
    const int sp_grp = t & 15;
    const int co_grp = t >> 4;

    __shared__ float Wl[16 * 128];
    __shared__ float Il[16 * 64];

    float acc[8][4];
#pragma unroll
    for (int i = 0; i < 8; ++i)
#pragma unroll
        for (int j = 0; j < 4; ++j) acc[i][j] = 0.f;

    for (int ch = 0; ch < 8; ++ch) {
        const int ci0 = ch * 16;
        __syncthreads();
        for (int i = t; i < 16 * 128; i += 256) Wl[i] = wt[ci0 * 128 + i];
        if (MODE == 0) {
            for (int i = t; i < 16 * 64; i += 256) {
                int ci = i >> 6, sp = i & 63;
                Il[i] = in[(size_t)(n * 128 + ci0 + ci) * HW + s0 + sp];
            }
        } else {
            int grp = t & 3, sp = t >> 2;
            const float4 v = *(const float4*)&in[(((size_t)(n * 8 + ch)) * HW + s0 + sp) * 16 + grp * 4];
            Il[(grp * 4 + 0) * 64 + sp] = v.x;
            Il[(grp * 4 + 1) * 64 + sp] = v.y;
            Il[(grp * 4 + 2) * 64 + sp] = v.z;
            Il[(grp * 4 + 3) * 64 + sp] = v.w;
        }
        __syncthreads();
#pragma unroll
        for (int ci = 0; ci < 16; ++ci) {
            float4 a0 = *(const float4*)&Wl[ci * 128 + co_grp * 8];
            float4 a1 = *(const float4*)&Wl[ci * 128 + co_grp * 8 + 4];
            float4 b  = *(const float4*)&Il[ci * 64 + sp_grp * 4];
            float av[8] = {a0.x, a0.y, a0.z, a0.w, a1.x, a1.y, a1.z, a1.w};
            float bv[4] = {b.x, b.y, b.z, b.w};
#pragma unroll
            for (int i = 0; i < 8; ++i)
#pragma unroll
                for (int j = 0; j < 4; ++j)
                    acc[i][j] = fmaf(av[i], bv[j], acc[i][j]);
        }
    }

#pragma unroll
    for (int i = 0; i < 8; ++i) {
        const int co = co_grp * 8 + i;
        const float bv = bias[co];
        if (MODE == 0) {
            const int hd = co >> 4, dd = co & 15;
#pragma unroll
            for (int j = 0; j < 4; ++j) {
                int s = s0 + sp_grp * 4 + j;
                out[((size_t)(n * 8 + hd) * HW + s) * 16 + dd] = acc[i][j] + bv;
            }
        } else {
#pragma unroll
            for (int j = 0; j < 4; ++j)
                out[(size_t)(n * 128 + co) * HW + s0 + sp_grp * 4 + j] = acc[i][j] + bv;
        }
    }
}

// ---------------------------------------------------------------------------
// Deformable attention, MLP-maximized: all 32 gathers issued before any use.
// Clamped unconditional loads; validity folded into bilinear weights
// (exact: valid is 0.0/1.0). grid: (32 slices, 100 tiles), block 256 =
// 64 sites x 4 chgrp, XCD-pinned (slice%8 = head -> XCD).
// v_s [nb][s][16] fp32; offs NHWC fp32; att NHWC-16 fp32.
// ---------------------------------------------------------------------------
__global__ __launch_bounds__(256, 2) void deform_attn_kernel(
    const float* __restrict__ v_s, const float* __restrict__ offs,
    const float* __restrict__ ref, float* __restrict__ att) {
    const int slice = blockIdx.x;
    const int n = slice >> 3, hd = slice & 7;
    const int t = threadIdx.x;
    const int s = blockIdx.y * 64 + (t >> 2);
    const int d0 = (t & 3) * 4;
    const int nb = n * 8 + hd;
    const float* vbase = v_s + (size_t)nb * (HW * 16) + d0;

    const float4 cv = *(const float4*)&v_s[((size_t)nb * HW + s) * 16 + d0];
    const float rx = ref[(size_t)(n * HW + s) * 2 + 0] * 80.f - 0.5f;
    const float ry = ref[(size_t)(n * HW + s) * 2 + 1] * 80.f - 0.5f;

    const int e = (s >= 3200) ? 1 : 0;
    const float* ob0 = offs + ((size_t)n * HW + (2 * s - e * HW)) * 128 + hd * 16 + e;

    // ---- phase 1: all offset loads ----
    float4 oxv[4], oyv[4];
#pragma unroll
    for (int i = 0; i < 4; ++i) {
        oxv[i] = *(const float4*)(ob0 + i * 4);
        oyv[i] = *(const float4*)(ob0 + 128 + i * 4);
    }
    float ox[8], oy[8];
#pragma unroll
    for (int i = 0; i < 4; ++i) {
        ox[2 * i] = oxv[i].x; ox[2 * i + 1] = oxv[i].z;
        oy[2 * i] = oyv[i].x; oy[2 * i + 1] = oyv[i].z;
    }

    // ---- phase 2: all coordinates/weights ----
    float wx1[8], wy1[8];
    int ix[8], iy[8];
#pragma unroll
    for (int p = 0; p < 8; ++p) {
        const float px = rx + ox[p];
        const float py = ry + oy[p];
        const float fx = floorf(px), fy = floorf(py);
        ix[p] = (int)fx; iy[p] = (int)fy;
        wx1[p] = px - fx; wy1[p] = py - fy;
    }

    // ---- phase 3: all 32 gathers (clamped, unconditional) ----
    float4 g[8][4];
#pragma unroll
    for (int p = 0; p < 8; ++p) {
        const int xc0 = min(max(ix[p], 0), 79),     xc1 = min(max(ix[p] + 1, 0), 79);
        const int yc0 = min(max(iy[p], 0), 79),     yc1 = min(max(iy[p] + 1, 0), 79);
        const int r0 = yc0 * 80, r1 = yc1 * 80;
        g[p][0] = *(const float4*)(vbase + (size_t)(r0 + xc0) * 16);
        g[p][1] = *(const float4*)(vbase + (size_t)(r0 + xc1) * 16);
        g[p][2] = *(const float4*)(vbase + (size_t)(r1 + xc0) * 16);
        g[p][3] = *(const float4*)(vbase + (size_t)(r1 + xc1) * 16);
    }

    // ---- phase 4: combine, score, softmax, output ----
    float4 sampled[8];
    float score[8];
#pragma unroll
    for (int p = 0; p < 8; ++p) {
        const float vx0 = (ix[p] >= 0 && ix[p] < Ww) ? 1.f : 0.f;
        const float vx1 = (ix[p] + 1 >= 0 && ix[p] + 1 < Ww) ? 1.f : 0.f;
        const float vy0 = (iy[p] >= 0 && iy[p] < Hh) ? 1.f : 0.f;
        const float vy1 = (iy[p] + 1 >= 0 && iy[p] + 1 < Hh) ? 1.f : 0.f;
        const float wx0 = 1.f - wx1[p], wy0 = 1.f - wy1[p];
        const float w00 = wx0 * wy0 * vx0 * vy0;
        const float w01 = wx1[p] * wy0 * vx1 * vy0;
        const float w10 = wx0 * wy1[p] * vx0 * vy1;
        const float w11 = wx1[p] * wy1[p] * vx1 * vy1;
        float4 sv;
        sv.x = g[p][0].x * w00 + g[p][1].x * w01 + g[p][2].x * w10 + g[p][3].x * w11;
        sv.y = g[p][0].y * w00 + g[p][1].y * w01 + g[p][2].y * w10 + g[p][3].y * w11;
        sv.z = g[p][0].z * w00 + g[p][1].z * w01 + g[p][2].z * w10 + g[p][3].z * w11;
        sv.w = g[p][0].w * w00 + g[p][1].w * w01 + g[p][2].w * w10 + g[p][3].w * w11;
        sampled[p] = sv;
        float sc = sv.x * cv.x + sv.y * cv.y + sv.z * cv.z + sv.w * cv.w;
        sc += __shfl_xor(sc, 1);
        sc += __shfl_xor(sc, 2);
        score[p] = sc;
    }

    float m = score[0];
#pragma unroll
    for (int p = 1; p < 8; ++p) m = fmaxf(m, score[p]);
    float sum = 0.f, aw[8];
#pragma unroll
    for (int p = 0; p < 8; ++p) {
        aw[p] = __expf(score[p] - m);
        sum += aw[p];
    }
    const float inv = 1.f / sum;
    float4 o = {0.f, 0.f, 0.f, 0.f};
#pragma unroll
    for (int p = 0; p < 8; ++p) {
        o.x += aw[p] * sampled[p].x;
        o.y += aw[p] * sampled[p].y;
        o.z += aw[p] * sampled[p].z;
        o.w += aw[p] * sampled[p].w;
    }
    o.x *= inv; o.y *= inv; o.z *= inv; o.w *= inv;

    *(float4*)&att[((size_t)nb * HW + s) * 16 + d0] = o;
}

// ---------------------------------------------------------------------------
extern "C" void kernel_launch(void* const* d_in, const int* in_sizes, int n_in,
                              void* d_out, int out_size, void* d_ws, size_t ws_size,
                              hipStream_t stream) {
    const float* query = (const float*)d_in[0];
    const float* value = (const float*)d_in[1];
    const float* ref   = (const float*)d_in[2];
    const float* co_w1 = (const float*)d_in[3];
    const float* co_b1 = (const float*)d_in[4];
    const float* co_w2 = (const float*)d_in[5];
    const float* co_b2 = (const float*)d_in[6];
    const float* co_w3 = (const float*)d_in[7];
    const float* co_b3 = (const float*)d_in[8];
    const float* co_w4 = (const float*)d_in[9];
    const float* co_b4 = (const float*)d_in[10];
    const float* val_w = (const float*)d_in[11];
    const float* val_b = (const float*)d_in[12];
    const float* out_w = (const float*)d_in[13];
    const float* out_b = (const float*)d_in[14];

    char* ws = (char*)d_ws;
    size_t o = 0;
    auto alloc = [&](size_t bytes) { char* p = ws + o; o += (bytes + 255) & ~(size_t)255; return p; };

    _Float16* wb2 = (_Float16*)alloc(147456 * 2);
    _Float16* wb3 = (_Float16*)alloc(147456 * 2);
    _Float16* wb4 = (_Float16*)alloc(147456 * 2);
    float* wtv = (float*)alloc(16384 * 4);
    float* wto = (float*)alloc(16384 * 4);
    char* vsR = alloc(3276800 * 4);            // v_s fp32 [32][6400][16]
    float* v_s = (float*)vsR;
    _Float16* wb1 = (_Float16*)vsR;            // alias: wb1 dead before v_s written
    char* R1 = alloc((size_t)NB * 8 * PS * 32 * 2);  // 13.77 MB
    _Float16* q_h = (_Float16*)R1;             // fp16 planar [4][8][PS][32]
    float* o4 = (float*)R1;                    // fp32 NHWC [4][6400][128]; q_h dead
    char* R2 = alloc((size_t)NB * 4 * PS * 32 * 2 * 2);  // 13.78 MB
    _Float16* hA = (_Float16*)R2;              // fp16 planar [4][4][PS][32]
    _Float16* hB = (_Float16*)(R2 + (size_t)NB * 4 * PS * 32 * 2);
    float* att = (float*)R2;                   // NHWC-16 fp32; used after hA/hB dead

    // fused prep: wblobs + 1x1 transposes + pad zeroing
    prep_kernel<<<4304, 256, 0, stream>>>(co_w1, co_w2, co_w3, co_w4, val_w, out_w,
                                          wb1, wb2, wb3, wb4, wtv, wto,
                                          (int*)q_h, (int*)hA, (int*)hB);

    // transpose query to chunked-planar fp16 (XCD-pinned like consumers)
    q_transpose<<<400, 256, 0, stream>>>(query, q_h);

    // conv1 (must precede val-conv: wb1 aliases v_s region)
    conv3x3_mfma<8, 1><<<400, 256, 0, stream>>>(q_h, wb1, co_b1, hA);

    // v = 1x1 conv(value) -> v_s (NHWC-16 fp32)
    conv1x1_kernel<0><<<dim3(100, NB), 256, 0, stream>>>(value, wtv, val_b, v_s);

    // rest of offset conv stack
    conv3x3_mfma<4, 1><<<400, 256, 0, stream>>>(hA, wb2, co_b2, hB);
    conv3x3_mfma<4, 1><<<400, 256, 0, stream>>>(hB, wb3, co_b3, hA);
    conv3x3_mfma<4, 2><<<400, 256, 0, stream>>>(hA, wb4, co_b4, o4);

    // deformable attention -> att (NHWC-16 fp32), XCD-pinned slices
    deform_attn_kernel<<<dim3(32, 100), 256, 0, stream>>>(v_s, o4, ref, att);

    // final 1x1 conv -> d_out (NCHW fp32)
    conv1x1_kernel<1><<<dim3(100, NB), 256, 0, stream>>>(att, wto, out_b, (float*)d_out);
}

// Round 11
// 270.297 us; speedup vs baseline: 1.3230x; 1.1090x over previous
//
#include <hip/hip_runtime.h>
#include <math.h>

#define Hh 80
#define Ww 80
#define HW 6400
#define PS 6724      // 82*82 padded spatial
#define NB 4

typedef _Float16 half8 __attribute__((ext_vector_type(8)));
typedef _Float16 half4v __attribute__((ext_vector_type(4)));
typedef float f32x16 __attribute__((ext_vector_type(16)));

// ---------------------------------------------------------------------------
// Fused prep: 4 conv3x3 MFMA A-blobs + 2 conv1x1 MFMA A-blobs (all fp16) +
// pad-zeroing of the chunked-planar activation buffers.
// conv3x3 blob: flat = (CT*NS + c*18 + tap*2 + h)*512 + lane*8 + j
//   co = CT*32 + (lane&31);  ci = c*32 + h*16 + (lane>>5)*8 + j
// conv1x1 blob: flat = ((CT*8 + c)*64 + lane)*8 + j
//   co = CT*32 + (lane&31);  ci = c*16 + (lane>>5)*8 + j
// ---------------------------------------------------------------------------
__device__ inline void wblob_one(const float* src, _Float16* dst, int CI, int d) {
    int NC = CI / 32;
    int j = d & 7;
    int l = (d >> 3) & 63;
    int h = (d >> 9) & 1;
    int rest = d >> 10;
    int tap = rest % 9;
    rest /= 9;
    int c = rest % NC;
    int CT = rest / NC;
    int co = CT * 32 + (l & 31);
    int ci = c * 32 + h * 16 + (l >> 5) * 8 + j;
    dst[d] = (_Float16)src[((size_t)co * CI + ci) * 9 + tap];
}

__device__ inline void wblob1x1_one(const float* src, _Float16* dst, int d) {
    int j = d & 7;
    int l = (d >> 3) & 63;
    int c = (d >> 9) & 7;
    int CT = d >> 12;
    int co = CT * 32 + (l & 31);
    int ci = c * 16 + (l >> 5) * 8 + j;
    dst[d] = (_Float16)src[co * 128 + ci];
}

__device__ inline int padsite(int p) {
    if (p < 82) return p;                       // row 0
    if (p < 164) return 81 * 82 + (p - 82);     // row 81
    if (p < 244) return (p - 163) * 82;         // col 0, rows 1..80
    return (p - 243) * 82 + 81;                 // col 81, rows 1..80
}

__global__ void prep_kernel(const float* __restrict__ w1, const float* __restrict__ w2,
                            const float* __restrict__ w3, const float* __restrict__ w4,
                            const float* __restrict__ vw, const float* __restrict__ ow,
                            _Float16* __restrict__ b1, _Float16* __restrict__ b2,
                            _Float16* __restrict__ b3, _Float16* __restrict__ b4,
                            _Float16* __restrict__ bv, _Float16* __restrict__ bo,
                            int* __restrict__ qh_i, int* __restrict__ hA_i,
                            int* __restrict__ hB_i) {
    int idx = blockIdx.x * 256 + threadIdx.x;
    if (idx < 294912) { wblob_one(w1, b1, 256, idx); return; }
    idx -= 294912;
    if (idx < 147456) { wblob_one(w2, b2, 128, idx); return; }
    idx -= 147456;
    if (idx < 147456) { wblob_one(w3, b3, 128, idx); return; }
    idx -= 147456;
    if (idx < 147456) { wblob_one(w4, b4, 128, idx); return; }
    idx -= 147456;
    if (idx < 16384) { wblob1x1_one(vw, bv, idx); return; }
    idx -= 16384;
    if (idx < 16384) { wblob1x1_one(ow, bo, idx); return; }
    idx -= 16384;
    if (idx < 165888) {  // q_h pads: 4n x 8c x 324 sites x 16 ints (32 halfs)
        int n = idx / 41472, rr = idx % 41472;
        int c = rr / 5184, r2 = rr % 5184;
        int p = r2 >> 4, k = r2 & 15;
        qh_i[((size_t)(n * 8 + c) * PS + padsite(p)) * 16 + k] = 0;
        return;
    }
    idx -= 165888;
    if (idx < 82944) {   // hA pads: 4n x 4c x 324 x 16 ints
        int n = idx / 20736, rr = idx % 20736;
        int c = rr / 5184, r2 = rr % 5184;
        int p = r2 >> 4, k = r2 & 15;
        hA_i[((size_t)(n * 4 + c) * PS + padsite(p)) * 16 + k] = 0;
        return;
    }
    idx -= 82944;
    if (idx < 82944) {
        int n = idx / 20736, rr = idx % 20736;
        int c = rr / 5184, r2 = rr % 5184;
        int p = r2 >> 4, k = r2 & 15;
        hB_i[((size_t)(n * 4 + c) * PS + padsite(p)) * 16 + k] = 0;
    }
}

// ---------------------------------------------------------------------------
// query fp32 NCHW -> fp16 chunked-planar [n][8c][82x82][32], XCD-pinned.
// grid (400), block 256: xcd = b&7 -> (n = xcd&3, half = xcd>>2).
// ---------------------------------------------------------------------------
__global__ __launch_bounds__(256) void q_transpose(
    const float* __restrict__ in, _Float16* __restrict__ out) {
    const int b = blockIdx.x;
    const int xcd = b & 7, n = xcd & 3, hi = xcd >> 2;
    const int s0 = hi * 3200 + (b >> 3) * 64;
    const int t = threadIdx.x;
    constexpr int CI = 256, ST = CI + 8;
    __shared__ _Float16 T[64 * ST];
    for (int idx = t; idx < 64 * CI; idx += 256) {
        int ci = idx >> 6, sl = idx & 63;
        T[sl * ST + ci] = (_Float16)in[((size_t)n * CI + ci) * HW + s0 + sl];
    }
    __syncthreads();
    for (int idx = t; idx < 64 * 32; idx += 256) {
        int q = idx & 31, sl = idx >> 5;
        int s = s0 + sl, yy = s / 80, xx = s % 80;
        int c = q >> 2, off = (q & 3) * 8;
        *(int4*)(out + ((size_t)(n * 8 + c) * PS + (yy + 1) * 82 + (xx + 1)) * 32 + off) =
            *(const int4*)(&T[sl * ST + q * 8]);
    }
}

// ---------------------------------------------------------------------------
// value fp32 NCHW -> fp16 rows [n][s][128], XCD-pinned. grid (400), block 256.
// ---------------------------------------------------------------------------
__global__ __launch_bounds__(256) void v_transpose(
    const float* __restrict__ in, _Float16* __restrict__ out) {
    const int b = blockIdx.x;
    const int xcd = b & 7, n = xcd & 3, hi = xcd >> 2;
    const int s0 = hi * 3200 + (b >> 3) * 64;
    const int t = threadIdx.x;
    constexpr int CI = 128, ST = CI + 8;
    __shared__ _Float16 T[64 * ST];
    for (int idx = t; idx < 64 * CI; idx += 256) {
        int ci = idx >> 6, sl = idx & 63;
        T[sl * ST + ci] = (_Float16)in[((size_t)n * CI + ci) * HW + s0 + sl];
    }
    __syncthreads();
    for (int idx = t; idx < 64 * 16; idx += 256) {
        int q = idx & 15, sl = idx >> 4;
        *(int4*)(out + ((size_t)n * HW + s0 + sl) * CI + q * 8) =
            *(const int4*)(&T[sl * ST + q * 8]);
    }
}

// ---------------------------------------------------------------------------
// MFMA implicit-GEMM 3x3 conv, pad=1, chunked-planar fp16 in ([n][c][82x82][32]).
// Barrier-free, no LDS, XCD-pinned. Block = 256 thr = 4 waves sharing ONE
// co-half over a 16x8 region; wave = 64co x 32sp (8x4). Depth-9 pipeline.
// grid: flat (400). b&7 -> XCD -> (n, image-half); b>>3 -> (coH, region).
// ACT 1: leaky -> chunked-planar fp16 [n][4c][PS][32].
// ACT 2: 10*tanh -> fp32 NHWC [n][6400][128].
// ---------------------------------------------------------------------------
template <int NCp, int ACT>
__global__ __launch_bounds__(256) void conv3x3_mfma(
    const _Float16* __restrict__ in, const _Float16* __restrict__ wblob,
    const float* __restrict__ bias, void* __restrict__ outp) {
    constexpr int NS = NCp * 18;
    const int b = blockIdx.x;
    const int xcd = b & 7, n = xcd & 3, hi = xcd >> 2;
    const int r = b >> 3;                    // 0..49
    const int coH = r & 1, j = r >> 1;       // j in [0,25)
    const int x0 = (j % 5) * 16, y0 = hi * 40 + (j / 5) * 8;
    const int t = threadIdx.x;
    const int w = t >> 6, l = t & 63;
    const int x0w = x0 + (w & 1) * 8, y0w = y0 + (w >> 1) * 4;
    const int lane31 = l & 31, lhalf = l >> 5;
    const int lx = lane31 & 7, ly = lane31 >> 3;

    const _Float16* p0 = in + ((size_t)(n * NCp) * PS + (y0w + ly + 1) * 82 + (x0w + lx + 1)) * 32 + lhalf * 8;
    const _Float16* wA0 = wblob + ((size_t)(coH * 2) * NS) * 512 + l * 8;
    const _Float16* wA1 = wA0 + (size_t)NS * 512;

    f32x16 acc0 = {}, acc1 = {};
    half8 bB[9], bA0[9], bA1[9];

    auto boff = [](int t2) -> size_t {
        int c = t2 / 18, u = t2 % 18;
        int tap = u >> 1, h = u & 1;
        int dy = tap / 3, dx = tap % 3;
        return (size_t)c * (PS * 32) + ((dy - 1) * 82 + (dx - 1)) * 32 + h * 16;
    };

#pragma unroll
    for (int t2 = 0; t2 < 9; ++t2) {
        bB[t2]  = *(const half8*)(p0 + boff(t2));
        bA0[t2] = *(const half8*)(wA0 + t2 * 512);
        bA1[t2] = *(const half8*)(wA1 + t2 * 512);
    }

#pragma unroll
    for (int t2 = 0; t2 < NS; ++t2) {
        const int slot = t2 % 9;
        acc0 = __builtin_amdgcn_mfma_f32_32x32x16_f16(bA0[slot], bB[slot], acc0, 0, 0, 0);
        acc1 = __builtin_amdgcn_mfma_f32_32x32x16_f16(bA1[slot], bB[slot], acc1, 0, 0, 0);
        if (t2 + 9 < NS) {
            const int t2p = t2 + 9;
            bB[slot]  = *(const half8*)(p0 + boff(t2p));
            bA0[slot] = *(const half8*)(wA0 + (size_t)t2p * 512);
            bA1[slot] = *(const half8*)(wA1 + (size_t)t2p * 512);
        }
    }

    // epilogue: D col(site)=lane&31, row(co)=(reg&3)+8*(reg>>2)+4*(lane>>5)
    const int y = y0w + ly, x = x0w + lx;
#pragma unroll
    for (int ct = 0; ct < 2; ++ct) {
        const f32x16& acc = ct ? acc1 : acc0;
#pragma unroll
        for (int q = 0; q < 4; ++q) {
            const int inner = 8 * q + 4 * lhalf;
            const int co0 = coH * 64 + ct * 32 + inner;
            float v[4];
#pragma unroll
            for (int i = 0; i < 4; ++i) {
                float vv = acc[q * 4 + i] + bias[co0 + i];
                if (ACT == 1) vv = (vv >= 0.f) ? vv : 0.1f * vv;
                else vv = 10.f * tanhf(vv);
                v[i] = vv;
            }
            if (ACT == 1) {
                half4v hv = {(_Float16)v[0], (_Float16)v[1], (_Float16)v[2], (_Float16)v[3]};
                const int c2 = coH * 2 + ct;
                *(half4v*)((_Float16*)outp +
                    ((size_t)(n * 4 + c2) * PS + (y + 1) * 82 + (x + 1)) * 32 + inner) = hv;
            } else {
                float4 fv = {v[0], v[1], v[2], v[3]};
                *(float4*)((float*)outp + ((size_t)n * HW + y * 80 + x) * 128 + co0) = fv;
            }
        }
    }
}

// ---------------------------------------------------------------------------
// MFMA 1x1 conv (K=128), fp16 rows [n][s][128] in, fp32 out. Barrier-free,
// XCD-pinned. Block 256 = 4 waves x 32 sites; wave = 64co (2 co-tiles).
// All 24 loads issued before the 16 MFMAs. grid: flat (400).
// MODE 0: out v_s fp32 [n*8+hd][s][16].  MODE 1: out fp32 NCHW.
// ---------------------------------------------------------------------------
template <int MODE>
__global__ __launch_bounds__(256) void conv1x1_mfma(
    const _Float16* __restrict__ in, const _Float16* __restrict__ wblob,
    const float* __restrict__ bias, float* __restrict__ outp) {
    const int b = blockIdx.x;
    const int xcd = b & 7, n = xcd & 3, hi = xcd >> 2;
    const int r = b >> 3;                    // 0..49
    const int coH = r & 1, strip = r >> 1;   // strip in [0,25)
    const int t = threadIdx.x;
    const int w = t >> 6, l = t & 63;
    const int lane31 = l & 31, lhalf = l >> 5;
    const int s = hi * 3200 + strip * 128 + w * 32 + lane31;

    const _Float16* pB = in + (size_t)(n * HW + s) * 128 + lhalf * 8;
    const _Float16* pA0 = wblob + (size_t)(coH * 2) * 8 * 512 + l * 8;
    const _Float16* pA1 = pA0 + 8 * 512;

    half8 bB[8], bA0[8], bA1[8];
#pragma unroll
    for (int c = 0; c < 8; ++c) {
        bB[c]  = *(const half8*)(pB + c * 16);
        bA0[c] = *(const half8*)(pA0 + (size_t)c * 512);
        bA1[c] = *(const half8*)(pA1 + (size_t)c * 512);
    }
    f32x16 acc0 = {}, acc1 = {};
#pragma unroll
    for (int c = 0; c < 8; ++c) {
        acc0 = __builtin_amdgcn_mfma_f32_32x32x16_f16(bA0[c], bB[c], acc0, 0, 0, 0);
        acc1 = __builtin_amdgcn_mfma_f32_32x32x16_f16(bA1[c], bB[c], acc1, 0, 0, 0);
    }

#pragma unroll
    for (int ct = 0; ct < 2; ++ct) {
        const f32x16& acc = ct ? acc1 : acc0;
#pragma unroll
        for (int q = 0; q < 4; ++q) {
            const int co0 = coH * 64 + ct * 32 + 8 * q + 4 * lhalf;
            if (MODE == 0) {
                const int hd = co0 >> 4, dd = co0 & 15;
                float4 fv = {acc[4 * q + 0] + bias[co0 + 0], acc[4 * q + 1] + bias[co0 + 1],
                             acc[4 * q + 2] + bias[co0 + 2], acc[4 * q + 3] + bias[co0 + 3]};
                *(float4*)&outp[((size_t)(n * 8 + hd) * HW + s) * 16 + dd] = fv;
            } else {
#pragma unroll
                for (int i = 0; i < 4; ++i)
                    outp[(size_t)(n * 128 + co0 + i) * HW + s] = acc[4 * q + i] + bias[co0 + i];
            }
        }
    }
}

// ---------------------------------------------------------------------------
// Deformable attention, MLP-maximized (all 32 gathers issued before use,
// clamped loads + validity folded into weights). XCD-pinned slices.
// grid: (32 slices, 100 tiles), block 256 = 64 sites x 4 chgrp.
// v_s [nb][s][16] fp32; offs NHWC fp32; att fp16 rows [n][s][128].
// ---------------------------------------------------------------------------
__global__ __launch_bounds__(256, 2) void deform_attn_kernel(
    const float* __restrict__ v_s, const float* __restrict__ offs,
    const float* __restrict__ ref, _Float16* __restrict__ att) {
    const int slice = blockIdx.x;
    const int n = slice >> 3, hd = slice & 7;
    const int t = threadIdx.x;
    const int s = blockIdx.y * 64 + (t >> 2);
    const int d0 = (t & 3) * 4;
    const int nb = n * 8 + hd;
    const float* vbase = v_s + (size_t)nb * (HW * 16) + d0;

    const float4 cv = *(const float4*)&v_s[((size_t)nb * HW + s) * 16 + d0];
    const float rx = ref[(size_t)(n * HW + s) * 2 + 0] * 80.f - 0.5f;
    const float ry = ref[(size_t)(n * HW + s) * 2 + 1] * 80.f - 0.5f;

    const int e = (s >= 3200) ? 1 : 0;
    const float* ob0 = offs + ((size_t)n * HW + (2 * s - e * HW)) * 128 + hd * 16 + e;

    // ---- phase 1: all offset loads ----
    float4 oxv[4], oyv[4];
#pragma unroll
    for (int i = 0; i < 4; ++i) {
        oxv[i] = *(const float4*)(ob0 + i * 4);
        oyv[i] = *(const float4*)(ob0 + 128 + i * 4);
    }
    float ox[8], oy[8];
#pragma unroll
    for (int i = 0; i < 4; ++i) {
        ox[2 * i] = oxv[i].x; ox[2 * i + 1] = oxv[i].z;
        oy[2 * i] = oyv[i].x; oy[2 * i + 1] = oyv[i].z;
    }

    // ---- phase 2: all coordinates/weights ----
    float wx1[8], wy1[8];
    int ix[8], iy[8];
#pragma unroll
    for (int p = 0; p < 8; ++p) {
        const float px = rx + ox[p];
        const float py = ry + oy[p];
        const float fx = floorf(px), fy = floorf(py);
        ix[p] = (int)fx; iy[p] = (int)fy;
        wx1[p] = px - fx; wy1[p] = py - fy;
    }

    // ---- phase 3: all 32 gathers (clamped, unconditional) ----
    float4 g[8][4];
#pragma unroll
    for (int p = 0; p < 8; ++p) {
        const int xc0 = min(max(ix[p], 0), 79),     xc1 = min(max(ix[p] + 1, 0), 79);
        const int yc0 = min(max(iy[p], 0), 79),     yc1 = min(max(iy[p] + 1, 0), 79);
        const int r0 = yc0 * 80, r1 = yc1 * 80;
        g[p][0] = *(const float4*)(vbase + (size_t)(r0 + xc0) * 16);
        g[p][1] = *(const float4*)(vbase + (size_t)(r0 + xc1) * 16);
        g[p][2] = *(const float4*)(vbase + (size_t)(r1 + xc0) * 16);
        g[p][3] = *(const float4*)(vbase + (size_t)(r1 + xc1) * 16);
    }

    // ---- phase 4: combine, score, softmax, output ----
    float4 sampled[8];
    float score[8];
#pragma unroll
    for (int p = 0; p < 8; ++p) {
        const float vx0 = (ix[p] >= 0 && ix[p] < Ww) ? 1.f : 0.f;
        const float vx1 = (ix[p] + 1 >= 0 && ix[p] + 1 < Ww) ? 1.f : 0.f;
        const float vy0 = (iy[p] >= 0 && iy[p] < Hh) ? 1.f : 0.f;
        const float vy1 = (iy[p] + 1 >= 0 && iy[p] + 1 < Hh) ? 1.f : 0.f;
        const float wx0 = 1.f - wx1[p], wy0 = 1.f - wy1[p];
        const float w00 = wx0 * wy0 * vx0 * vy0;
        const float w01 = wx1[p] * wy0 * vx1 * vy0;
        const float w10 = wx0 * wy1[p] * vx0 * vy1;
        const float w11 = wx1[p] * wy1[p] * vx1 * vy1;
        float4 sv;
        sv.x = g[p][0].x * w00 + g[p][1].x * w01 + g[p][2].x * w10 + g[p][3].x * w11;
        sv.y = g[p][0].y * w00 + g[p][1].y * w01 + g[p][2].y * w10 + g[p][3].y * w11;
        sv.z = g[p][0].z * w00 + g[p][1].z * w01 + g[p][2].z * w10 + g[p][3].z * w11;
        sv.w = g[p][0].w * w00 + g[p][1].w * w01 + g[p][2].w * w10 + g[p][3].w * w11;
        sampled[p] = sv;
        float sc = sv.x * cv.x + sv.y * cv.y + sv.z * cv.z + sv.w * cv.w;
        sc += __shfl_xor(sc, 1);
        sc += __shfl_xor(sc, 2);
        score[p] = sc;
    }

    float m = score[0];
#pragma unroll
    for (int p = 1; p < 8; ++p) m = fmaxf(m, score[p]);
    float sum = 0.f, aw[8];
#pragma unroll
    for (int p = 0; p < 8; ++p) {
        aw[p] = __expf(score[p] - m);
        sum += aw[p];
    }
    const float inv = 1.f / sum;
    float4 o = {0.f, 0.f, 0.f, 0.f};
#pragma unroll
    for (int p = 0; p < 8; ++p) {
        o.x += aw[p] * sampled[p].x;
        o.y += aw[p] * sampled[p].y;
        o.z += aw[p] * sampled[p].z;
        o.w += aw[p] * sampled[p].w;
    }
    o.x *= inv; o.y *= inv; o.z *= inv; o.w *= inv;

    half4v hv = {(_Float16)o.x, (_Float16)o.y, (_Float16)o.z, (_Float16)o.w};
    *(half4v*)&att[((size_t)n * HW + s) * 128 + hd * 16 + d0] = hv;
}

// ---------------------------------------------------------------------------
extern "C" void kernel_launch(void* const* d_in, const int* in_sizes, int n_in,
                              void* d_out, int out_size, void* d_ws, size_t ws_size,
                              hipStream_t stream) {
    const float* query = (const float*)d_in[0];
    const float* value = (const float*)d_in[1];
    const float* ref   = (const float*)d_in[2];
    const float* co_w1 = (const float*)d_in[3];
    const float* co_b1 = (const float*)d_in[4];
    const float* co_w2 = (const float*)d_in[5];
    const float* co_b2 = (const float*)d_in[6];
    const float* co_w3 = (const float*)d_in[7];
    const float* co_b3 = (const float*)d_in[8];
    const float* co_w4 = (const float*)d_in[9];
    const float* co_b4 = (const float*)d_in[10];
    const float* val_w = (const float*)d_in[11];
    const float* val_b = (const float*)d_in[12];
    const float* out_w = (const float*)d_in[13];
    const float* out_b = (const float*)d_in[14];

    char* ws = (char*)d_ws;
    size_t o = 0;
    auto alloc = [&](size_t bytes) { char* p = ws + o; o += (bytes + 255) & ~(size_t)255; return p; };

    _Float16* wb2 = (_Float16*)alloc(147456 * 2);
    _Float16* wb3 = (_Float16*)alloc(147456 * 2);
    _Float16* wb4 = (_Float16*)alloc(147456 * 2);
    _Float16* wbv = (_Float16*)alloc(16384 * 2);
    _Float16* wbo = (_Float16*)alloc(16384 * 2);
    char* vsR = alloc(3276800 * 4);            // v_s fp32 [32][6400][16]
    float* v_s = (float*)vsR;
    _Float16* wb1 = (_Float16*)vsR;            // alias: wb1 dead before v_s written
    _Float16* v_h = (_Float16*)alloc((size_t)NB * HW * 128 * 2);  // 6.55 MB
    char* R1 = alloc((size_t)NB * 8 * PS * 32 * 2);  // 13.77 MB
    _Float16* q_h = (_Float16*)R1;             // fp16 planar [4][8][PS][32]
    float* o4 = (float*)R1;                    // fp32 NHWC [4][6400][128]; q_h dead
    char* R2 = alloc((size_t)NB * 4 * PS * 32 * 2 * 2);  // 13.78 MB
    _Float16* hA = (_Float16*)R2;              // fp16 planar [4][4][PS][32]
    _Float16* hB = (_Float16*)(R2 + (size_t)NB * 4 * PS * 32 * 2);
    _Float16* att_h = (_Float16*)R2;           // fp16 [4][6400][128]; hA dead by then

    // fused prep: wblobs + pad zeroing
    prep_kernel<<<4304, 256, 0, stream>>>(co_w1, co_w2, co_w3, co_w4, val_w, out_w,
                                          wb1, wb2, wb3, wb4, wbv, wbo,
                                          (int*)q_h, (int*)hA, (int*)hB);

    // transposes (XCD-pinned like consumers)
    q_transpose<<<400, 256, 0, stream>>>(query, q_h);
    v_transpose<<<400, 256, 0, stream>>>(value, v_h);

    // conv1 (must precede val-conv: wb1 aliases v_s region)
    conv3x3_mfma<8, 1><<<400, 256, 0, stream>>>(q_h, wb1, co_b1, hA);

    // v = 1x1 conv(value) -> v_s (NHWC-16 fp32)
    conv1x1_mfma<0><<<400, 256, 0, stream>>>(v_h, wbv, val_b, v_s);

    // rest of offset conv stack
    conv3x3_mfma<4, 1><<<400, 256, 0, stream>>>(hA, wb2, co_b2, hB);
    conv3x3_mfma<4, 1><<<400, 256, 0, stream>>>(hB, wb3, co_b3, hA);
    conv3x3_mfma<4, 2><<<400, 256, 0, stream>>>(hA, wb4, co_b4, o4);

    // deformable attention -> att_h (fp16 rows), XCD-pinned slices
    deform_attn_kernel<<<dim3(32, 100), 256, 0, stream>>>(v_s, o4, ref, att_h);

    // final 1x1 conv -> d_out (NCHW fp32)
    conv1x1_mfma<1><<<400, 256, 0, stream>>>(att_h, wbo, out_b, (float*)d_out);
}